// Round 13
// baseline (429.855 us; speedup 1.0000x reference)
//
#include <hip/hip_runtime.h>
#include <cstdint>
#include <cstddef>

#define B_   2
#define S_   2048
#define H_   16
#define D_   128
#define HID_ 2048

typedef __bf16 bf16;
typedef unsigned short u16;
typedef bf16 bf16x4 __attribute__((ext_vector_type(4)));
typedef bf16 bf16x8 __attribute__((ext_vector_type(8)));
typedef u16  u16x8  __attribute__((ext_vector_type(8)));
typedef float f32x4 __attribute__((ext_vector_type(4)));

__device__ unsigned g_work;   // work-stealing counter; zeroed by k_tables each launch

// flash item tables: 18 items per bh, heavy-first, makespan-balanced (R12)
__device__ const int it_qx[18]  = {7,7,6,4,4,2,6,6,5,5,5,3,3,1,7,7,0,2};
__device__ const int it_t0[18]  = {0,10,0,0,10,0,10,19,0,8,16,0,8,0,20,26,0,10};
__device__ const int it_t1[18]  = {10,20,10,10,20,10,19,28,8,16,24,8,16,8,26,32,4,12};
__device__ const int it_dst[18] = {0,1,0,0,8,0,4,5,0,6,7,0,9,0,2,3,0,10};
__device__ const int mg_qx[6]  = {7,6,5,4,3,2};
__device__ const int mg_np[6]  = {4,3,3,2,2,2};
__device__ const int mg_ss[6]  = {0,3,5,7,8,9};
__device__ const int mg_mlf[24] = {0,1,14,15,  2,6,7,0,  8,9,10,0,  3,4,0,0,  11,12,0,0,  5,17,0,0};

__device__ __forceinline__ f32x4 mfma16(bf16x8 a, bf16x8 b, f32x4 c){
  return __builtin_amdgcn_mfma_f32_16x16x32_bf16(a, b, c, 0, 0, 0);
}

__device__ __forceinline__ void gload_lds16(const void* g, void* l){
  __builtin_amdgcn_global_load_lds((const __attribute__((address_space(1))) void*)g,
                                   (__attribute__((address_space(3))) void*)l, 16, 0, 0);
}

__device__ __forceinline__ void bar_lgkm(){
  asm volatile("s_waitcnt lgkmcnt(0)" ::: "memory");
  __builtin_amdgcn_s_barrier();
}
__device__ __forceinline__ void bar_full(){
  asm volatile("s_waitcnt vmcnt(0) lgkmcnt(0)" ::: "memory");
  __builtin_amdgcn_s_barrier();
}

// ---------------- RoPE tables (+ work counter reset) ----------------
__global__ void k_tables(float* __restrict__ cosT, float* __restrict__ sinT){
  if (blockIdx.x == 0 && threadIdx.x == 0) g_work = 0u;
  int id = blockIdx.x*256 + threadIdx.x;      // S*64 = 131072 exact
  int p = id >> 6, i = id & 63;
  double f = (double)p * pow(10000.0, -(double)i/64.0);
  cosT[id] = (float)cos(f);
  sinT[id] = (float)sin(f);
}

// ---------------- compact masked-row indices: gidx[b][rank]=row, cnt[b] ----------------
__global__ void k_compact(const float* __restrict__ smask, int* __restrict__ gidx, int* __restrict__ cnt){
  const int b = blockIdx.x;       // 2 blocks, 64 threads
  const int lane = threadIdx.x;
  int base = 0;
  for (int i = 0; i < 32; ++i){
    int row = i*64 + lane;
    bool m = smask[(size_t)b*S_ + row] != 0.f;
    unsigned long long bits = __ballot(m);
    int rank = __popcll(bits & ((1ull << lane) - 1ull));
    if (m) gidx[b*S_ + base + rank] = row;
    base += __popcll(bits);
  }
  if (lane == 0) cnt[b] = base;
}

// ---------------- fused fp32 -> bf16 converts (5 segments: samat + 4 weights) ----------------
__global__ void k_cvt_all(const float* __restrict__ a1, bf16* __restrict__ o1,
                          const float* __restrict__ w0, bf16* __restrict__ q0,
                          const float* __restrict__ w1, bf16* __restrict__ q1,
                          const float* __restrict__ w2, bf16* __restrict__ q2,
                          const float* __restrict__ w3, bf16* __restrict__ q3){
  const float* src; bf16* dst; int n4;
  switch (blockIdx.y){
    case 0: src = a1; dst = o1; n4 = 2097152; break;
    case 1: src = w0; dst = q0; n4 = 1048576; break;
    case 2: src = w1; dst = q1; n4 = 1048576; break;
    case 3: src = w2; dst = q2; n4 = 1048576; break;
    default: src = w3; dst = q3; n4 = 1048576; break;
  }
  int i = blockIdx.x*256 + threadIdx.x;
  if (i >= n4) return;
  f32x4 v = *reinterpret_cast<const f32x4*>(src + (size_t)i*4);
  bf16x4 o;
  o[0]=(bf16)v[0]; o[1]=(bf16)v[1]; o[2]=(bf16)v[2]; o[3]=(bf16)v[3];
  *reinterpret_cast<bf16x4*>(dst + (size_t)i*4) = o;
}

// ---- hidden [B][S][HID] f32 -> hiddenT [B][HID][S] bf16 + hidden_bf + hm_init ----
// hm_init[row] = mask ? 0 : hidden_bf[row]  (masked rows overwritten by compacted GEMM)
__global__ __launch_bounds__(256) void k_transpose_cvt(const float* __restrict__ in, bf16* __restrict__ out,
                                                       bf16* __restrict__ hbf, bf16* __restrict__ hm,
                                                       const float* __restrict__ smask){
  __shared__ bf16 t[64][72];
  const int tid = threadIdx.x;
  const int b = blockIdx.z, j0 = blockIdx.x*64, s0 = blockIdx.y*64;
  #pragma unroll
  for (int u0 = 0; u0 < 4; ++u0){
    int u = u0*256 + tid;
    int r = u >> 4, c4 = (u & 15)*4;
    size_t off = ((size_t)b*S_ + s0 + r)*HID_ + j0 + c4;
    f32x4 v = *reinterpret_cast<const f32x4*>(in + off);
    bf16x4 o; o[0]=(bf16)v[0]; o[1]=(bf16)v[1]; o[2]=(bf16)v[2]; o[3]=(bf16)v[3];
    *reinterpret_cast<bf16x4*>(&t[r][c4]) = o;
    *reinterpret_cast<bf16x4*>(hbf + off) = o;
    bool msk = smask[(size_t)b*S_ + s0 + r] != 0.f;
    bf16x4 z; z[0]=(bf16)0.f; z[1]=(bf16)0.f; z[2]=(bf16)0.f; z[3]=(bf16)0.f;
    *reinterpret_cast<bf16x4*>(hm + off) = msk ? z : o;
  }
  __syncthreads();
  #pragma unroll
  for (int u0 = 0; u0 < 4; ++u0){
    int u = u0*256 + tid;
    int r = u >> 4, c4 = (u & 15)*4;    // r: j-local, c4: s-local
    bf16x4 o;
    o[0] = t[c4+0][r]; o[1] = t[c4+1][r]; o[2] = t[c4+2][r]; o[3] = t[c4+3][r];
    *reinterpret_cast<bf16x4*>(out + ((size_t)b*HID_ + j0 + r)*S_ + s0 + c4) = o;
  }
}

// ---------------- NT GEMM 128x128 (dense): EPI 0 bf16, EPI 2 fp32 ----------------
template<int EPI>
__global__ __launch_bounds__(256) void k_gemm_nt(
    const bf16* __restrict__ A, const bf16* __restrict__ Bm, void* __restrict__ Cv,
    int Kd, size_t sAz, size_t sBz, size_t sCz, int N,
    const float* __restrict__ mask, const float* __restrict__ hid)
{
  const int tid = threadIdx.x;
  const int wid = tid >> 6, lane = tid & 63;
  const int g = lane >> 4, li = lane & 15;
  const int z = blockIdx.z;
  const int m0 = blockIdx.y*128, n0 = blockIdx.x*128;
  const int wm = wid >> 1, wn = wid & 1;
  const bf16* Ab = A + (size_t)z*sAz;
  const bf16* Bb = Bm + (size_t)z*sBz;

  __shared__ bf16 lA[128*64];
  __shared__ bf16 lB[128*64];

  f32x4 acc[4][4];
  #pragma unroll
  for (int i=0;i<4;++i)
    #pragma unroll
    for (int j=0;j<4;++j)
      acc[i][j] = {0.f,0.f,0.f,0.f};

  for (int k0 = 0; k0 < Kd; k0 += 64){
    #pragma unroll
    for (int j=0;j<4;++j){
      int ci = j*256 + tid;
      int r = ci >> 3, cb = ci & 7;
      gload_lds16(Ab + (size_t)(m0 + r)*Kd + k0 + cb*8, (char*)lA + (j*256 + wid*64)*16);
      gload_lds16(Bb + (size_t)(n0 + r)*Kd + k0 + cb*8, (char*)lB + (j*256 + wid*64)*16);
    }
    __syncthreads();
    #pragma unroll
    for (int kk=0;kk<2;++kk){
      bf16x8 af[4], bfm[4];
      #pragma unroll
      for (int i=0;i<4;++i){
        af[i]  = *reinterpret_cast<const bf16x8*>(&lA[(wm*64 + i*16 + li)*64 + kk*32 + g*8]);
        bfm[i] = *reinterpret_cast<const bf16x8*>(&lB[(wn*64 + i*16 + li)*64 + kk*32 + g*8]);
      }
      #pragma unroll
      for (int i=0;i<4;++i)
        #pragma unroll
        for (int j=0;j<4;++j)
          acc[i][j] = mfma16(af[i], bfm[j], acc[i][j]);
    }
    __syncthreads();
  }

  #pragma unroll
  for (int i=0;i<4;++i){
    #pragma unroll
    for (int j=0;j<4;++j){
      #pragma unroll
      for (int v=0;v<4;++v){
        int row = m0 + wm*64 + i*16 + g*4 + v;
        int col = n0 + wn*64 + j*16 + li;
        float x = acc[i][j][v];
        if (EPI == 0){
          ((bf16*)Cv)[(size_t)row*N + col] = (bf16)x;
        } else if (EPI == 2){
          ((float*)Cv)[(size_t)row*N + col] = x;
        }
      }
    }
  }
}

// ---------------- compacted-row GEMM: hm[gidx[r]] = samat[gidx[r],:] @ hiddenT ----------------
// grid (16, 16, 2): per z, (mt,xb) from linear id with z-flipped mt so active blocks
// spread 1/CU regardless of cnt. Blocks with m0 >= cnt exit immediately.
__global__ __launch_bounds__(256) void k_gemm_cmp(
    const bf16* __restrict__ A, const bf16* __restrict__ Bm, bf16* __restrict__ Cv,
    const int* __restrict__ gidx, const int* __restrict__ cnt)
{
  const int tid = threadIdx.x;
  const int z = blockIdx.z;
  const int l = blockIdx.x + (blockIdx.y << 4);        // 0..255
  const int mt = z ? (15 - (l & 15)) : (l & 15);
  const int xb = l >> 4;
  const int m0 = mt*128, n0 = xb*128;
  const int c = cnt[z];
  if (m0 >= c) return;

  const int wid = tid >> 6, lane = tid & 63;
  const int g = lane >> 4, li = lane & 15;
  const int wm = wid >> 1, wn = wid & 1;
  const bf16* Ab = A + (size_t)z*S_*HID_;
  const bf16* Bb = Bm + (size_t)z*S_*HID_;

  __shared__ bf16 lA[128*64];
  __shared__ bf16 lB[128*64];
  __shared__ int sidx[128];
  if (tid < 128) sidx[tid] = gidx[z*S_ + min(m0 + tid, c - 1)];
  __syncthreads();

  f32x4 acc[4][4];
  #pragma unroll
  for (int i=0;i<4;++i)
    #pragma unroll
    for (int j=0;j<4;++j)
      acc[i][j] = {0.f,0.f,0.f,0.f};

  for (int k0 = 0; k0 < HID_; k0 += 64){
    #pragma unroll
    for (int j=0;j<4;++j){
      int ci = j*256 + tid;
      int r = ci >> 3, cb = ci & 7;
      gload_lds16(Ab + (size_t)sidx[r]*HID_ + k0 + cb*8, (char*)lA + (j*256 + wid*64)*16);
      gload_lds16(Bb + (size_t)(n0 + r)*HID_ + k0 + cb*8, (char*)lB + (j*256 + wid*64)*16);
    }
    __syncthreads();
    #pragma unroll
    for (int kk=0;kk<2;++kk){
      bf16x8 af[4], bfm[4];
      #pragma unroll
      for (int i=0;i<4;++i){
        af[i]  = *reinterpret_cast<const bf16x8*>(&lA[(wm*64 + i*16 + li)*64 + kk*32 + g*8]);
        bfm[i] = *reinterpret_cast<const bf16x8*>(&lB[(wn*64 + i*16 + li)*64 + kk*32 + g*8]);
      }
      #pragma unroll
      for (int i=0;i<4;++i)
        #pragma unroll
        for (int j=0;j<4;++j)
          acc[i][j] = mfma16(af[i], bfm[j], acc[i][j]);
    }
    __syncthreads();
  }

  #pragma unroll
  for (int i=0;i<4;++i){
    #pragma unroll
    for (int j=0;j<4;++j){
      #pragma unroll
      for (int v=0;v<4;++v){
        int lr = wm*64 + i*16 + g*4 + v;
        int col = n0 + wn*64 + j*16 + li;
        if (m0 + lr < c)
          Cv[(size_t)z*S_*HID_ + (size_t)sidx[lr]*HID_ + col] = (bf16)acc[i][j][v];
      }
    }
  }
}

// ---------------- G34 engine: 256x256 NT GEMM, 8 waves, m201 4-phase body ----------------
__global__ __launch_bounds__(512) void k_g8(
    const bf16* __restrict__ A, const bf16* __restrict__ Bm,
    bf16* __restrict__ Ck, bf16* __restrict__ Cvv)
{
  const int tid = threadIdx.x;
  const int wid = tid >> 6, lane = tid & 63;
  const int g = lane >> 4, li = lane & 15;
  const int wm = wid >> 2, wn = wid & 3;
  const int sb = (blockIdx.x & 7)*32 + (blockIdx.x >> 3);
  const int m0 = (sb >> 4)*256, n0 = (sb & 15)*256;
  const bf16* Ab = A  + (size_t)m0*HID_;
  const bf16* Bb = Bm + (size_t)n0*HID_;

  __shared__ bf16 lA[2][256*64];
  __shared__ bf16 lB[2][256*64];

  const int rr0 = tid >> 3, cc = tid & 7;
  const int rr1 = rr0 + 64;
  const int cx0 = cc ^ (rr0 & 7);
  const int cx1 = cc ^ (rr1 & 7);

  f32x4 acc[8][4];
  #pragma unroll
  for (int i=0;i<8;++i)
    #pragma unroll
    for (int j=0;j<4;++j) acc[i][j] = {0.f,0.f,0.f,0.f};

  auto stage = [&](int buf, int kt, int matsel, int half){
    const bf16* s = matsel ? Bb : Ab;
    char* dbase = (char*)(matsel ? lB[buf] : lA[buf]) + half*16384;
    gload_lds16(s + (size_t)(half*128 + rr0)*HID_ + kt*64 + cx0*8, dbase + (wid*64)*16);
    gload_lds16(s + (size_t)(half*128 + rr1)*HID_ + kt*64 + cx1*8, dbase + (512 + wid*64)*16);
  };
  auto rdA = [&](int buf, int i, int kh){
    int row = wm*128 + i*16 + li;
    return *reinterpret_cast<const bf16x8*>((const char*)lA[buf] + row*128 + (((kh*4 + g) ^ (row & 7))*16));
  };
  auto rdB = [&](int buf, int j, int kh){
    int row = wn*64 + j*16 + li;
    return *reinterpret_cast<const bf16x8*>((const char*)lB[buf] + row*128 + (((kh*4 + g) ^ (row & 7))*16));
  };

  const int NT = HID_ >> 6;
  stage(0,0,0,0); stage(0,0,0,1); stage(0,0,1,0); stage(0,0,1,1);

  int cur = 0;
  for (int kt = 0; kt < NT; ++kt){
    const bool more = (kt+1 < NT);
    bf16x8 af[4], bfr[4];

    if (more){
      stage(cur^1, kt+1, 0, 0);
      stage(cur^1, kt+1, 0, 1);
      stage(cur^1, kt+1, 1, 0);
      asm volatile("s_waitcnt vmcnt(6)" ::: "memory");
    } else {
      asm volatile("s_waitcnt vmcnt(0)" ::: "memory");
    }
    __builtin_amdgcn_s_barrier();

    // phase 0
    #pragma unroll
    for (int i=0;i<4;++i) af[i] = rdA(cur, i, 0);
    #pragma unroll
    for (int j=0;j<4;++j) bfr[j] = rdB(cur, j, 0);
    if (more) stage(cur^1, kt+1, 1, 1);
    __builtin_amdgcn_s_barrier();
    asm volatile("s_waitcnt lgkmcnt(0)" ::: "memory");
    __builtin_amdgcn_sched_barrier(0);
    __builtin_amdgcn_s_setprio(1);
    #pragma unroll
    for (int i=0;i<4;++i)
      #pragma unroll
      for (int j=0;j<4;++j) acc[i][j] = mfma16(af[i], bfr[j], acc[i][j]);
    __builtin_amdgcn_s_setprio(0);
    __builtin_amdgcn_s_barrier();

    // phase 1
    #pragma unroll
    for (int i=0;i<4;++i) af[i] = rdA(cur, i+4, 0);
    __builtin_amdgcn_s_barrier();
    asm volatile("s_waitcnt lgkmcnt(0)" ::: "memory");
    __builtin_amdgcn_sched_barrier(0);
    __builtin_amdgcn_s_setprio(1);
    #pragma unroll
    for (int i=0;i<4;++i)
      #pragma unroll
      for (int j=0;j<4;++j) acc[i+4][j] = mfma16(af[i], bfr[j], acc[i+4][j]);
    __builtin_amdgcn_s_setprio(0);
    __builtin_amdgcn_s_barrier();

    // phase 2
    #pragma unroll
    for (int i=0;i<4;++i) af[i] = rdA(cur, i, 1);
    #pragma unroll
    for (int j=0;j<4;++j) bfr[j] = rdB(cur, j, 1);
    __builtin_amdgcn_s_barrier();
    asm volatile("s_waitcnt lgkmcnt(0)" ::: "memory");
    __builtin_amdgcn_sched_barrier(0);
    __builtin_amdgcn_s_setprio(1);
    #pragma unroll
    for (int i=0;i<4;++i)
      #pragma unroll
      for (int j=0;j<4;++j) acc[i][j] = mfma16(af[i], bfr[j], acc[i][j]);
    __builtin_amdgcn_s_setprio(0);
    __builtin_amdgcn_s_barrier();

    // phase 3
    #pragma unroll
    for (int i=0;i<4;++i) af[i] = rdA(cur, i+4, 1);
    __builtin_amdgcn_s_barrier();
    asm volatile("s_waitcnt lgkmcnt(0)" ::: "memory");
    __builtin_amdgcn_sched_barrier(0);
    __builtin_amdgcn_s_setprio(1);
    #pragma unroll
    for (int i=0;i<4;++i)
      #pragma unroll
      for (int j=0;j<4;++j) acc[i+4][j] = mfma16(af[i], bfr[j], acc[i+4][j]);
    __builtin_amdgcn_s_setprio(0);
    __builtin_amdgcn_s_barrier();

    cur ^= 1;
  }

  #pragma unroll
  for (int i=0;i<8;++i){
    #pragma unroll
    for (int j=0;j<4;++j){
      #pragma unroll
      for (int v=0;v<4;++v){
        int row = m0 + wm*128 + i*16 + g*4 + v;
        int col = n0 + wn*64 + j*16 + li;
        float x = acc[i][j][v];
        if (col < 2048) Ck[(size_t)row*2048 + col] = (bf16)x;
        else            Cvv[(size_t)row*2048 + col - 2048] = (bf16)x;
      }
    }
  }
}

// ---------------- RoPE in place (optional output scale) ----------------
__global__ void k_rope(bf16* __restrict__ X, const float* __restrict__ cosT,
                       const float* __restrict__ sinT, const int* __restrict__ pos, float scale){
  int id = blockIdx.x*256 + threadIdx.x;
  int d4 = (id & 15)*4;
  int h  = (id >> 4) & 15;
  int s  = (id >> 8) & 2047;
  int b  = id >> 19;
  int p = pos ? pos[b*S_ + s] : s;
  size_t base = (((size_t)b*S_ + s)*H_ + h)*D_ + d4;
  f32x4 c  = *reinterpret_cast<const f32x4*>(cosT + (size_t)p*64 + d4);
  f32x4 sn = *reinterpret_cast<const f32x4*>(sinT + (size_t)p*64 + d4);
  bf16x4 x1 = *reinterpret_cast<bf16x4*>(X + base);
  bf16x4 x2 = *reinterpret_cast<bf16x4*>(X + base + 64);
  bf16x4 o1, o2;
  #pragma unroll
  for (int i=0;i<4;++i){
    float a = (float)x1[i], bb = (float)x2[i];
    o1[i] = (bf16)((a*c[i] - bb*sn[i])*scale);
    o2[i] = (bf16)((bb*c[i] + a*sn[i])*scale);
  }
  *reinterpret_cast<bf16x4*>(X + base) = o1;
  *reinterpret_cast<bf16x4*>(X + base + 64) = o2;
}

// ---------------- causal flash attention (R12 structure, unchanged) ----------------
__global__ __launch_bounds__(512,2) void k_flash(const bf16* __restrict__ Q, const bf16* __restrict__ K,
                                                 const bf16* __restrict__ V, bf16* __restrict__ O,
                                                 bf16* __restrict__ OPb, float* __restrict__ ML)
{
  const int tid = threadIdx.x;
  const int wid = tid >> 6, lane = tid & 63;
  const int g = lane >> 4, li = lane & 15;

  __shared__ bf16 Klds[2][64*128];
  __shared__ char VtB[128*128];
  __shared__ bf16 Plds[8][32*64];
  int* sip = (int*)&Plds[0][0];

  const int dc = tid & 15, kvp = tid >> 4;

  for (;;) {
    if (tid == 0) *sip = (int)atomicAdd(&g_work, 1u);
    __syncthreads();
    const int w = *sip;
    if (w >= 576) return;

    const int idx = w >> 5, bh = w & 31;
    const int qx = it_qx[idx], t0 = it_t0[idx], t1 = it_t1[idx];

    const int qb = qx * 256;
    const size_t headoff = ((size_t)(bh >> 4)*S_*H_ + (bh & 15))*D_;
    const bf16* Kh = K + headoff;
    const u16*  Vh = (const u16*)(V + headoff);

    bf16x8 qf[2][4];
    #pragma unroll
    for (int rb=0;rb<2;++rb){
      const bf16* Qp = Q + headoff + (size_t)(qb + wid*32 + rb*16 + li)*H_*D_;
      #pragma unroll
      for (int kc=0;kc<4;++kc)
        qf[rb][kc] = *reinterpret_cast<const bf16x8*>(Qp + kc*32 + g*8);
    }

    float mrun[2][4], lrun[2][4];
    f32x4 acc[2][8];
    #pragma unroll
    for (int rb=0;rb<2;++rb){
      #pragma unroll
      for (int v=0;v<4;++v){ mrun[rb][v] = -1e30f; lrun[rb][v] = 0.f; }
      #pragma unroll
      for (int fn=0;fn<8;++fn) acc[rb][fn] = {0.f,0.f,0.f,0.f};
    }

    u16x8 vp[2];
    auto stageK = [&](int buf, int t){
      #pragma unroll
      for (int j=0;j<2;++j){
        int ci = j*512 + tid;
        int r = ci >> 4, cb = ci & 15;
        const char* src = (const char*)(Kh + (size_t)(t*64 + r)*H_*D_) + ((cb ^ (r & 7)) * 16);
        gload_lds16(src, (char*)Klds[buf] + (j*512 + wid*64)*16);
      }
    };
    auto loadV = [&](int t){
      const u16* sp = Vh + (size_t)(t*64 + kvp*2)*H_*D_ + dc*8;
      vp[0] = *reinterpret_cast<const u16x8*>(sp);
      vp[1] = *reinterpret_cast<const u16x8*>(sp + H_*D_);
    };
    auto writeVtB = [&](){
      #pragma unroll
      for (int e=0;e<8;++e){
        int r = dc*8 + e;
        int swz = (r ^ (r >> 3)) & 7;
        int addr = r*128 + (((kvp >> 2) ^ swz) << 4) + ((kvp << 2) & 12);
        *reinterpret_cast<uint32_t*>(VtB + addr) =
            (uint32_t)vp[0][e] | ((uint32_t)vp[1][e] << 16);
      }
    };

    stageK(0, t0);
    loadV(t0);
    writeVtB();
    bar_full();

    int cur = 0;
    for (int t=t0; t<t1; ++t){
      const bool more = (t+1 < t1);
      if (more){ stageK(cur^1, t+1); loadV(t+1); }

      f32x4 sc[2][4];
      #pragma unroll
      for (int fc=0;fc<4;++fc){
        int r = fc*16 + li;
        bf16x8 kf[4];
        #pragma unroll
        for (int kc=0;kc<4;++kc)
          kf[kc] = *reinterpret_cast<const bf16x8*>((const char*)Klds[cur] + r*256 + (((4*kc + g) ^ (r & 7))*16));
        __builtin_amdgcn_s_setprio(1);
        #pragma unroll
        for (int rb=0;rb<2;++rb){
          f32x4 s = {0.f,0.f,0.f,0.f};
          #pragma unroll
          for (int kc=0;kc<4;++kc)
            s = mfma16(qf[rb][kc], kf[kc], s);
          sc[rb][fc] = s;
        }
        __builtin_amdgcn_s_setprio(0);
      }

      const int c0 = t*64;
      if (t >= 4*qx){
        #pragma unroll
        for (int rb=0;rb<2;++rb){
          const int rowg = qb + wid*32 + rb*16 + g*4;
          #pragma unroll
          for (int fc=0;fc<4;++fc){
            int col = c0 + fc*16 + li;
            #pragma unroll
            for (int v=0;v<4;++v)
              if (col > rowg + v) sc[rb][fc][v] = -1e30f;
          }
        }
      }

      #pragma unroll
      for (int rb=0;rb<2;++rb){
        float tm[4];
        #pragma unroll
        for (int v=0;v<4;++v){
          float m2 = fmaxf(fmaxf(sc[rb][0][v], sc[rb][1][v]), fmaxf(sc[rb][2][v], sc[rb][3][v]));
          m2 = fmaxf(m2, __shfl_xor(m2, 1));
          m2 = fmaxf(m2, __shfl_xor(m2, 2));
          m2 = fmaxf(m2, __shfl_xor(m2, 4));
          m2 = fmaxf(m2, __shfl_xor(m2, 8));
          tm[v] = m2;
        }
        bool need = false;
        #pragma unroll
        for (int v=0;v<4;++v) need = need || (tm[v] > mrun[rb][v] + 8.f);
        if (__any(need)){
          float al[4];
          #pragma unroll
          for (int v=0;v<4;++v){
            float mnew = fmaxf(mrun[rb][v], tm[v]);
            al[v] = __expf(mrun[rb][v] - mnew);
            mrun[rb][v] = mnew;
            lrun[rb][v] *= al[v];
          }
          #pragma unroll
          for (int fn=0;fn<8;++fn)
            #pragma unroll
            for (int v=0;v<4;++v) acc[rb][fn][v] *= al[v];
        }
        float rs[4] = {0.f,0.f,0.f,0.f};
        #pragma unroll
        for (int fc=0;fc<4;++fc){
          #pragma unroll
          for (int v=0;v<4;++v){
            float p = __expf(sc[rb][fc][v] - mrun[rb][v]);
            rs[v] += p;
            int prow = rb*16 + g*4 + v;
            int pchunk = (fc*2 + (li>>3)) ^ (prow & 7);
            Plds[wid][prow*64 + pchunk*8 + (li & 7)] = (bf16)p;
          }
        }
        #pragma unroll
        for (int v=0;v<4;++v){
          float r = rs[v];
          r += __shfl_xor(r, 1); r += __shfl_xor(r, 2);
          r += __shfl_xor(r, 4); r += __shfl_xor(r, 8);
          lrun[rb][v] += r;
        }
      }

      bf16x8 pa[2][2];
      #pragma unroll
      for (int rb=0;rb<2;++rb)
        #pragma unroll
        for (int kc=0;kc<2;++kc)
          pa[rb][kc] = *reinterpret_cast<const bf16x8*>(
              &Plds[wid][(rb*16 + li)*64 + (((kc*4 + g) ^ (li & 7))<<3)]);
      #pragma unroll
      for (int fn=0;fn<8;++fn){
        int r = fn*16 + li;
        int swz = (r ^ (r >> 3)) & 7;
        bf16x8 bv[2];
        #pragma unroll
        for (int kc=0;kc<2;++kc)
          bv[kc] = *reinterpret_cast<const bf16x8*>(VtB + r*128 + (((kc*4 + g) ^ swz) << 4));
        __builtin_amdgcn_s_setprio(1);
        #pragma unroll
        for (int rb=0;rb<2;++rb)
          #pragma unroll
          for (int kc=0;kc<2;++kc)
            acc[rb][fn] = mfma16(pa[rb][kc], bv[kc], acc[rb][fn]);
        __builtin_amdgcn_s_setprio(0);
      }

      if (more){
        bar_lgkm();
        writeVtB();
      }
      bar_full();
      cur ^= 1;
    }

    const int dsel = it_dst[idx];
    float* MLd = ML + (size_t)(bh*18 + idx)*512;
    if (dsel == 0){
      #pragma unroll
      for (int rb=0;rb<2;++rb){
        #pragma unroll
        for (int v=0;v<4;++v){
          float inv = 1.f / lrun[rb][v];
          int rl = wid*32 + rb*16 + g*4 + v;
          bf16* dst = O + headoff + (size_t)(qb + rl)*H_*D_ + li;
          #pragma unroll
          for (int fn=0;fn<8;++fn)
            dst[fn*16] = (bf16)(acc[rb][fn][v] * inv);
          if (li == 0){ MLd[rl*2] = mrun[rb][v]; MLd[rl*2+1] = lrun[rb][v]; }
        }
      }
    } else {
      bf16* Od = OPb + (size_t)(bh*10 + dsel - 1)*256*128;
      #pragma unroll
      for (int rb=0;rb<2;++rb){
        #pragma unroll
        for (int v=0;v<4;++v){
          float inv = 1.f / lrun[rb][v];
          int rl = wid*32 + rb*16 + g*4 + v;
          #pragma unroll
          for (int fn=0;fn<8;++fn)
            Od[rl*128 + fn*16 + li] = (bf16)(acc[rb][fn][v] * inv);
          if (li == 0){ MLd[rl*2] = mrun[rb][v]; MLd[rl*2+1] = lrun[rb][v]; }
        }
      }
    }
  }
}

// ---------------- merge split partials into O ----------------
__global__ __launch_bounds__(256) void k_merge(const bf16* __restrict__ OPb, const float* __restrict__ ML,
                                               bf16* __restrict__ O){
  const int gid = blockIdx.x;         // 192 = 6 groups x 32 bh
  const int gsel = gid >> 5, bh = gid & 31;
  const int qx = mg_qx[gsel], np = mg_np[gsel], ss = mg_ss[gsel];
  const int b = bh >> 4, h = bh & 15;
  const int row = threadIdx.x;

  float m[4], l[4], wgt[4];
  #pragma unroll
  for (int j=0;j<4;++j){
    if (j < np){
      const float* mlp = ML + (size_t)(bh*18 + mg_mlf[gsel*4 + j])*512 + row*2;
      m[j] = mlp[0]; l[j] = mlp[1];
    } else { m[j] = -1e30f; l[j] = 0.f; }
  }
  float mm = fmaxf(fmaxf(m[0], m[1]), fmaxf(m[2], m[3]));
  float wsum = 0.f;
  #pragma unroll
  for (int j=0;j<4;++j){ wgt[j] = l[j]*__expf(m[j]-mm); wsum += wgt[j]; }
  float inv = 1.f/wsum;
  #pragma unroll
  for (int j=0;j<4;++j) wgt[j] *= inv;

  bf16* dst = O + (((size_t)b*S_ + qx*256 + row)*H_ + h)*D_;
  const bf16* s1 = OPb + (size_t)(bh*10 + ss + 0)*256*128 + row*128;
  const bf16* s2 = OPb + (size_t)(bh*10 + ss + 1)*256*128 + row*128;
  const bf16* s3 = OPb + (size_t)(bh*10 + ss + 2)*256*128 + row*128;
  #pragma unroll
  for (int c=0;c<128;c+=8){
    bf16x8 a = *reinterpret_cast<const bf16x8*>(dst + c);
    float acc8[8];
    #pragma unroll
    for (int i=0;i<8;++i) acc8[i] = (float)a[i]*wgt[0];
    bf16x8 p1 = *reinterpret_cast<const bf16x8*>(s1 + c);
    #pragma unroll
    for (int i=0;i<8;++i) acc8[i] += (float)p1[i]*wgt[1];
    if (np > 2){
      bf16x8 p2 = *reinterpret_cast<const bf16x8*>(s2 + c);
      #pragma unroll
      for (int i=0;i<8;++i) acc8[i] += (float)p2[i]*wgt[2];
    }
    if (np > 3){
      bf16x8 p3 = *reinterpret_cast<const bf16x8*>(s3 + c);
      #pragma unroll
      for (int i=0;i<8;++i) acc8[i] += (float)p3[i]*wgt[3];
    }
    bf16x8 o;
    #pragma unroll
    for (int i=0;i<8;++i) o[i] = (bf16)acc8[i];
    *reinterpret_cast<bf16x8*>(dst + c) = o;
  }
}

extern "C" void kernel_launch(void* const* d_in, const int* in_sizes, int n_in,
                              void* d_out, int out_size, void* d_ws, size_t ws_size,
                              hipStream_t stream)
{
  (void)in_sizes; (void)n_in; (void)out_size; (void)ws_size;
  const float* hid   = (const float*)d_in[0];
  const float* smask = (const float*)d_in[1];
  const float* samat = (const float*)d_in[2];
  const int*   pos   = (const int*)d_in[4];
  const float* Wq = (const float*)d_in[5];
  const float* Wk = (const float*)d_in[6];
  const float* Wv = (const float*)d_in[7];
  const float* Wo = (const float*)d_in[8];
  float* out = (float*)d_out;
  char* ws = (char*)d_ws;

  const size_t SZ_TAB = (size_t)S_*64*4;        // 512 KB per table
  const size_t SZ_BSH = (size_t)B_*S_*HID_*2;   // 16 MB bf16 [B,S,HID]
  float* cosT = (float*)(ws);
  float* sinT = (float*)(ws + SZ_TAB);
  bf16* buf1 = (bf16*)(ws + 2*SZ_TAB);                 // hidden_bf -> v
  bf16* buf2 = (bf16*)(ws + 2*SZ_TAB + 1*SZ_BSH);      // hiddenT  -> k
  bf16* buf3 = (bf16*)(ws + 2*SZ_TAB + 2*SZ_BSH);      // samat_bf -> q
  bf16* buf4 = (bf16*)(ws + 2*SZ_TAB + 3*SZ_BSH);      // hm -> attention O
  bf16* Wqb = (bf16*)(ws + 2*SZ_TAB + 4*SZ_BSH);
  bf16* Wkb = Wqb + (size_t)HID_*HID_;
  bf16* Wvb = Wkb + (size_t)HID_*HID_;
  bf16* Wob = Wvb + (size_t)HID_*HID_;
  // flash scratch aliases dead Wq/Wk/Wv region: 320 slots x 64KB = 20MB + ML 1.2MB <= 24MB
  bf16* OPb = Wqb;
  float* ML = (float*)((char*)Wqb + (size_t)320*256*128*2);
  // compaction tables after Wob (8 MB weight) — 16 KB + 8 B
  int* gidx = (int*)(Wob + (size_t)HID_*HID_);
  int* cnt  = gidx + B_*S_;

  k_tables<<<512,256,0,stream>>>(cosT, sinT);
  k_compact<<<2,64,0,stream>>>(smask, gidx, cnt);
  k_cvt_all<<<dim3(8192,5),256,0,stream>>>(samat, buf3,
                                           Wq, Wqb, Wk, Wkb, Wv, Wvb, Wo, Wob);
  k_transpose_cvt<<<dim3(32,32,2),256,0,stream>>>(hid, buf2, buf1, buf4, smask);

  // G1 (compacted): hm[masked rows] = samat @ hiddenT ; unmasked rows pre-filled by transpose
  k_gemm_cmp<<<dim3(16,16,2),256,0,stream>>>(buf3, buf2, buf4, gidx, cnt);
  // G2: q = hidden_bf @ Wq^T
  k_gemm_nt<0><<<dim3(16,32,1),256,0,stream>>>(buf1, Wqb, buf3, 2048, 0,0,0, 2048, nullptr, nullptr);
  k_rope<<<4096,256,0,stream>>>(buf3, cosT, sinT, pos, 0.08838834764831845f);  // q: pre-scaled
  // G3+G4 fused: [k|v] = hm @ [Wk|Wv]^T  (m201-body 256^2 engine, 256 blocks)
  k_g8<<<dim3(256),512,0,stream>>>(buf4, Wkb, buf2, buf1);
  k_rope<<<4096,256,0,stream>>>(buf2, cosT, sinT, nullptr, 1.0f);
  // attention: O -> buf4 (hm dead); split partials -> OPb/ML
  k_flash<<<dim3(512),512,0,stream>>>(buf3, buf2, buf1, buf4, OPb, ML);
  k_merge<<<dim3(192),256,0,stream>>>(OPb, ML, buf4);
  // G5: out = O @ Wo^T -> fp32
  k_gemm_nt<2><<<dim3(16,32,1),256,0,stream>>>(buf4, Wob, out, 2048, 0,0,0, 2048, nullptr, nullptr);
}

// Round 14
// 414.281 us; speedup vs baseline: 1.0376x; 1.0376x over previous
//
#include <hip/hip_runtime.h>
#include <cstdint>
#include <cstddef>

#define B_   2
#define S_   2048
#define H_   16
#define D_   128
#define HID_ 2048

typedef __bf16 bf16;
typedef unsigned short u16;
typedef bf16 bf16x4 __attribute__((ext_vector_type(4)));
typedef bf16 bf16x8 __attribute__((ext_vector_type(8)));
typedef u16  u16x8  __attribute__((ext_vector_type(8)));
typedef float f32x4 __attribute__((ext_vector_type(4)));

__device__ unsigned g_work;   // work-stealing counter; zeroed by k_tables each launch

// flash item tables: 18 items per bh, heavy-first, makespan-balanced (R12)
__device__ const int it_qx[18]  = {7,7,6,4,4,2,6,6,5,5,5,3,3,1,7,7,0,2};
__device__ const int it_t0[18]  = {0,10,0,0,10,0,10,19,0,8,16,0,8,0,20,26,0,10};
__device__ const int it_t1[18]  = {10,20,10,10,20,10,19,28,8,16,24,8,16,8,26,32,4,12};
__device__ const int it_dst[18] = {0,1,0,0,8,0,4,5,0,6,7,0,9,0,2,3,0,10};
__device__ const int mg_qx[6]  = {7,6,5,4,3,2};
__device__ const int mg_np[6]  = {4,3,3,2,2,2};
__device__ const int mg_ss[6]  = {0,3,5,7,8,9};
__device__ const int mg_mlf[24] = {0,1,14,15,  2,6,7,0,  8,9,10,0,  3,4,0,0,  11,12,0,0,  5,17,0,0};

__device__ __forceinline__ f32x4 mfma16(bf16x8 a, bf16x8 b, f32x4 c){
  return __builtin_amdgcn_mfma_f32_16x16x32_bf16(a, b, c, 0, 0, 0);
}

__device__ __forceinline__ void gload_lds16(const void* g, void* l){
  __builtin_amdgcn_global_load_lds((const __attribute__((address_space(1))) void*)g,
                                   (__attribute__((address_space(3))) void*)l, 16, 0, 0);
}

__device__ __forceinline__ void bar_lgkm(){
  asm volatile("s_waitcnt lgkmcnt(0)" ::: "memory");
  __builtin_amdgcn_s_barrier();
}
__device__ __forceinline__ void bar_full(){
  asm volatile("s_waitcnt vmcnt(0) lgkmcnt(0)" ::: "memory");
  __builtin_amdgcn_s_barrier();
}

// ---------------- RoPE tables (+ work counter reset) ----------------
__global__ void k_tables(float* __restrict__ cosT, float* __restrict__ sinT){
  if (blockIdx.x == 0 && threadIdx.x == 0) g_work = 0u;
  int id = blockIdx.x*256 + threadIdx.x;      // S*64 = 131072 exact
  int p = id >> 6, i = id & 63;
  double f = (double)p * pow(10000.0, -(double)i/64.0);
  cosT[id] = (float)cos(f);
  sinT[id] = (float)sin(f);
}

// ---------------- fused fp32 -> bf16 converts (5 segments: samat + 4 weights) ----------------
__global__ void k_cvt_all(const float* __restrict__ a1, bf16* __restrict__ o1,
                          const float* __restrict__ w0, bf16* __restrict__ q0,
                          const float* __restrict__ w1, bf16* __restrict__ q1,
                          const float* __restrict__ w2, bf16* __restrict__ q2,
                          const float* __restrict__ w3, bf16* __restrict__ q3){
  const float* src; bf16* dst; int n4;
  switch (blockIdx.y){
    case 0: src = a1; dst = o1; n4 = 2097152; break;
    case 1: src = w0; dst = q0; n4 = 1048576; break;
    case 2: src = w1; dst = q1; n4 = 1048576; break;
    case 3: src = w2; dst = q2; n4 = 1048576; break;
    default: src = w3; dst = q3; n4 = 1048576; break;
  }
  int i = blockIdx.x*256 + threadIdx.x;
  if (i >= n4) return;
  f32x4 v = *reinterpret_cast<const f32x4*>(src + (size_t)i*4);
  bf16x4 o;
  o[0]=(bf16)v[0]; o[1]=(bf16)v[1]; o[2]=(bf16)v[2]; o[3]=(bf16)v[3];
  *reinterpret_cast<bf16x4*>(dst + (size_t)i*4) = o;
}

// ---- hidden [B][S][HID] f32 -> hiddenT [B][HID][S] bf16 + hidden_bf (fused convert) ----
__global__ __launch_bounds__(256) void k_transpose_cvt(const float* __restrict__ in, bf16* __restrict__ out,
                                                       bf16* __restrict__ hbf){
  __shared__ bf16 t[64][72];
  const int tid = threadIdx.x;
  const int b = blockIdx.z, j0 = blockIdx.x*64, s0 = blockIdx.y*64;
  #pragma unroll
  for (int u0 = 0; u0 < 4; ++u0){
    int u = u0*256 + tid;
    int r = u >> 4, c4 = (u & 15)*4;
    size_t off = ((size_t)b*S_ + s0 + r)*HID_ + j0 + c4;
    f32x4 v = *reinterpret_cast<const f32x4*>(in + off);
    bf16x4 o; o[0]=(bf16)v[0]; o[1]=(bf16)v[1]; o[2]=(bf16)v[2]; o[3]=(bf16)v[3];
    *reinterpret_cast<bf16x4*>(&t[r][c4]) = o;
    *reinterpret_cast<bf16x4*>(hbf + off) = o;
  }
  __syncthreads();
  #pragma unroll
  for (int u0 = 0; u0 < 4; ++u0){
    int u = u0*256 + tid;
    int r = u >> 4, c4 = (u & 15)*4;    // r: j-local, c4: s-local
    bf16x4 o;
    o[0] = t[c4+0][r]; o[1] = t[c4+1][r]; o[2] = t[c4+2][r]; o[3] = t[c4+3][r];
    *reinterpret_cast<bf16x4*>(out + ((size_t)b*HID_ + j0 + r)*S_ + s0 + c4) = o;
  }
}

// ---------------- NT GEMM 128x128: C[M,N] = A[M,K] * B[N,K]^T, bf16 in, fp32 acc ----------------
// EPI 0: bf16. EPI 1: += (1-mask[row])*hid[row,col], bf16 (batched). EPI 2: fp32.
template<int EPI>
__global__ __launch_bounds__(256) void k_gemm_nt(
    const bf16* __restrict__ A, const bf16* __restrict__ Bm, void* __restrict__ Cv,
    int Kd, size_t sAz, size_t sBz, size_t sCz, int N,
    const float* __restrict__ mask, const float* __restrict__ hid)
{
  const int tid = threadIdx.x;
  const int wid = tid >> 6, lane = tid & 63;
  const int g = lane >> 4, li = lane & 15;
  const int z = blockIdx.z;
  const int m0 = blockIdx.y*128, n0 = blockIdx.x*128;
  const int wm = wid >> 1, wn = wid & 1;
  const bf16* Ab = A + (size_t)z*sAz;
  const bf16* Bb = Bm + (size_t)z*sBz;

  __shared__ bf16 lA[128*64];
  __shared__ bf16 lB[128*64];

  f32x4 acc[4][4];
  #pragma unroll
  for (int i=0;i<4;++i)
    #pragma unroll
    for (int j=0;j<4;++j)
      acc[i][j] = {0.f,0.f,0.f,0.f};

  for (int k0 = 0; k0 < Kd; k0 += 64){
    #pragma unroll
    for (int j=0;j<4;++j){
      int ci = j*256 + tid;
      int r = ci >> 3, cb = ci & 7;
      gload_lds16(Ab + (size_t)(m0 + r)*Kd + k0 + cb*8, (char*)lA + (j*256 + wid*64)*16);
      gload_lds16(Bb + (size_t)(n0 + r)*Kd + k0 + cb*8, (char*)lB + (j*256 + wid*64)*16);
    }
    __syncthreads();
    #pragma unroll
    for (int kk=0;kk<2;++kk){
      bf16x8 af[4], bfm[4];
      #pragma unroll
      for (int i=0;i<4;++i){
        af[i]  = *reinterpret_cast<const bf16x8*>(&lA[(wm*64 + i*16 + li)*64 + kk*32 + g*8]);
        bfm[i] = *reinterpret_cast<const bf16x8*>(&lB[(wn*64 + i*16 + li)*64 + kk*32 + g*8]);
      }
      #pragma unroll
      for (int i=0;i<4;++i)
        #pragma unroll
        for (int j=0;j<4;++j)
          acc[i][j] = mfma16(af[i], bfm[j], acc[i][j]);
    }
    __syncthreads();
  }

  #pragma unroll
  for (int i=0;i<4;++i){
    #pragma unroll
    for (int j=0;j<4;++j){
      #pragma unroll
      for (int v=0;v<4;++v){
        int row = m0 + wm*64 + i*16 + g*4 + v;
        int col = n0 + wn*64 + j*16 + li;
        float x = acc[i][j][v];
        if (EPI == 1){
          x += (1.f - mask[z*S_ + row]) * hid[((size_t)z*S_ + row)*HID_ + col];
          ((bf16*)Cv)[(size_t)z*sCz + (size_t)row*N + col] = (bf16)x;
        } else if (EPI == 0){
          ((bf16*)Cv)[(size_t)row*N + col] = (bf16)x;
        } else if (EPI == 2){
          ((float*)Cv)[(size_t)row*N + col] = x;
        }
      }
    }
  }
}

// ---------------- G34 engine: 256x256 NT GEMM, 8 waves, m201 4-phase body ----------------
__global__ __launch_bounds__(512) void k_g8(
    const bf16* __restrict__ A, const bf16* __restrict__ Bm,
    bf16* __restrict__ Ck, bf16* __restrict__ Cvv)
{
  const int tid = threadIdx.x;
  const int wid = tid >> 6, lane = tid & 63;
  const int g = lane >> 4, li = lane & 15;
  const int wm = wid >> 2, wn = wid & 3;
  const int sb = (blockIdx.x & 7)*32 + (blockIdx.x >> 3);
  const int m0 = (sb >> 4)*256, n0 = (sb & 15)*256;
  const bf16* Ab = A  + (size_t)m0*HID_;
  const bf16* Bb = Bm + (size_t)n0*HID_;

  __shared__ bf16 lA[2][256*64];
  __shared__ bf16 lB[2][256*64];

  const int rr0 = tid >> 3, cc = tid & 7;
  const int rr1 = rr0 + 64;
  const int cx0 = cc ^ (rr0 & 7);
  const int cx1 = cc ^ (rr1 & 7);

  f32x4 acc[8][4];
  #pragma unroll
  for (int i=0;i<8;++i)
    #pragma unroll
    for (int j=0;j<4;++j) acc[i][j] = {0.f,0.f,0.f,0.f};

  auto stage = [&](int buf, int kt, int matsel, int half){
    const bf16* s = matsel ? Bb : Ab;
    char* dbase = (char*)(matsel ? lB[buf] : lA[buf]) + half*16384;
    gload_lds16(s + (size_t)(half*128 + rr0)*HID_ + kt*64 + cx0*8, dbase + (wid*64)*16);
    gload_lds16(s + (size_t)(half*128 + rr1)*HID_ + kt*64 + cx1*8, dbase + (512 + wid*64)*16);
  };
  auto rdA = [&](int buf, int i, int kh){
    int row = wm*128 + i*16 + li;
    return *reinterpret_cast<const bf16x8*>((const char*)lA[buf] + row*128 + (((kh*4 + g) ^ (row & 7))*16));
  };
  auto rdB = [&](int buf, int j, int kh){
    int row = wn*64 + j*16 + li;
    return *reinterpret_cast<const bf16x8*>((const char*)lB[buf] + row*128 + (((kh*4 + g) ^ (row & 7))*16));
  };

  const int NT = HID_ >> 6;
  stage(0,0,0,0); stage(0,0,0,1); stage(0,0,1,0); stage(0,0,1,1);

  int cur = 0;
  for (int kt = 0; kt < NT; ++kt){
    const bool more = (kt+1 < NT);
    bf16x8 af[4], bfr[4];

    if (more){
      stage(cur^1, kt+1, 0, 0);
      stage(cur^1, kt+1, 0, 1);
      stage(cur^1, kt+1, 1, 0);
      asm volatile("s_waitcnt vmcnt(6)" ::: "memory");
    } else {
      asm volatile("s_waitcnt vmcnt(0)" ::: "memory");
    }
    __builtin_amdgcn_s_barrier();

    // phase 0
    #pragma unroll
    for (int i=0;i<4;++i) af[i] = rdA(cur, i, 0);
    #pragma unroll
    for (int j=0;j<4;++j) bfr[j] = rdB(cur, j, 0);
    if (more) stage(cur^1, kt+1, 1, 1);
    __builtin_amdgcn_s_barrier();
    asm volatile("s_waitcnt lgkmcnt(0)" ::: "memory");
    __builtin_amdgcn_sched_barrier(0);
    __builtin_amdgcn_s_setprio(1);
    #pragma unroll
    for (int i=0;i<4;++i)
      #pragma unroll
      for (int j=0;j<4;++j) acc[i][j] = mfma16(af[i], bfr[j], acc[i][j]);
    __builtin_amdgcn_s_setprio(0);
    __builtin_amdgcn_s_barrier();

    // phase 1
    #pragma unroll
    for (int i=0;i<4;++i) af[i] = rdA(cur, i+4, 0);
    __builtin_amdgcn_s_barrier();
    asm volatile("s_waitcnt lgkmcnt(0)" ::: "memory");
    __builtin_amdgcn_sched_barrier(0);
    __builtin_amdgcn_s_setprio(1);
    #pragma unroll
    for (int i=0;i<4;++i)
      #pragma unroll
      for (int j=0;j<4;++j) acc[i+4][j] = mfma16(af[i], bfr[j], acc[i+4][j]);
    __builtin_amdgcn_s_setprio(0);
    __builtin_amdgcn_s_barrier();

    // phase 2
    #pragma unroll
    for (int i=0;i<4;++i) af[i] = rdA(cur, i, 1);
    #pragma unroll
    for (int j=0;j<4;++j) bfr[j] = rdB(cur, j, 1);
    __builtin_amdgcn_s_barrier();
    asm volatile("s_waitcnt lgkmcnt(0)" ::: "memory");
    __builtin_amdgcn_sched_barrier(0);
    __builtin_amdgcn_s_setprio(1);
    #pragma unroll
    for (int i=0;i<4;++i)
      #pragma unroll
      for (int j=0;j<4;++j) acc[i][j] = mfma16(af[i], bfr[j], acc[i][j]);
    __builtin_amdgcn_s_setprio(0);
    __builtin_amdgcn_s_barrier();

    // phase 3
    #pragma unroll
    for (int i=0;i<4;++i) af[i] = rdA(cur, i+4, 1);
    __builtin_amdgcn_s_barrier();
    asm volatile("s_waitcnt lgkmcnt(0)" ::: "memory");
    __builtin_amdgcn_sched_barrier(0);
    __builtin_amdgcn_s_setprio(1);
    #pragma unroll
    for (int i=0;i<4;++i)
      #pragma unroll
      for (int j=0;j<4;++j) acc[i+4][j] = mfma16(af[i], bfr[j], acc[i+4][j]);
    __builtin_amdgcn_s_setprio(0);
    __builtin_amdgcn_s_barrier();

    cur ^= 1;
  }

  #pragma unroll
  for (int i=0;i<8;++i){
    #pragma unroll
    for (int j=0;j<4;++j){
      #pragma unroll
      for (int v=0;v<4;++v){
        int row = m0 + wm*128 + i*16 + g*4 + v;
        int col = n0 + wn*64 + j*16 + li;
        float x = acc[i][j][v];
        if (col < 2048) Ck[(size_t)row*2048 + col] = (bf16)x;
        else            Cvv[(size_t)row*2048 + col - 2048] = (bf16)x;
      }
    }
  }
}

// ---------------- RoPE in place (optional output scale) ----------------
__global__ void k_rope(bf16* __restrict__ X, const float* __restrict__ cosT,
                       const float* __restrict__ sinT, const int* __restrict__ pos, float scale){
  int id = blockIdx.x*256 + threadIdx.x;
  int d4 = (id & 15)*4;
  int h  = (id >> 4) & 15;
  int s  = (id >> 8) & 2047;
  int b  = id >> 19;
  int p = pos ? pos[b*S_ + s] : s;
  size_t base = (((size_t)b*S_ + s)*H_ + h)*D_ + d4;
  f32x4 c  = *reinterpret_cast<const f32x4*>(cosT + (size_t)p*64 + d4);
  f32x4 sn = *reinterpret_cast<const f32x4*>(sinT + (size_t)p*64 + d4);
  bf16x4 x1 = *reinterpret_cast<bf16x4*>(X + base);
  bf16x4 x2 = *reinterpret_cast<bf16x4*>(X + base + 64);
  bf16x4 o1, o2;
  #pragma unroll
  for (int i=0;i<4;++i){
    float a = (float)x1[i], bb = (float)x2[i];
    o1[i] = (bf16)((a*c[i] - bb*sn[i])*scale);
    o2[i] = (bf16)((bb*c[i] + a*sn[i])*scale);
  }
  *reinterpret_cast<bf16x4*>(X + base) = o1;
  *reinterpret_cast<bf16x4*>(X + base + 64) = o2;
}

// ---------------- causal flash attention (R12 structure, unchanged) ----------------
__global__ __launch_bounds__(512,2) void k_flash(const bf16* __restrict__ Q, const bf16* __restrict__ K,
                                                 const bf16* __restrict__ V, bf16* __restrict__ O,
                                                 bf16* __restrict__ OPb, float* __restrict__ ML)
{
  const int tid = threadIdx.x;
  const int wid = tid >> 6, lane = tid & 63;
  const int g = lane >> 4, li = lane & 15;

  __shared__ bf16 Klds[2][64*128];
  __shared__ char VtB[128*128];
  __shared__ bf16 Plds[8][32*64];
  int* sip = (int*)&Plds[0][0];

  const int dc = tid & 15, kvp = tid >> 4;

  for (;;) {
    if (tid == 0) *sip = (int)atomicAdd(&g_work, 1u);
    __syncthreads();
    const int w = *sip;
    if (w >= 576) return;

    const int idx = w >> 5, bh = w & 31;
    const int qx = it_qx[idx], t0 = it_t0[idx], t1 = it_t1[idx];

    const int qb = qx * 256;
    const size_t headoff = ((size_t)(bh >> 4)*S_*H_ + (bh & 15))*D_;
    const bf16* Kh = K + headoff;
    const u16*  Vh = (const u16*)(V + headoff);

    bf16x8 qf[2][4];
    #pragma unroll
    for (int rb=0;rb<2;++rb){
      const bf16* Qp = Q + headoff + (size_t)(qb + wid*32 + rb*16 + li)*H_*D_;
      #pragma unroll
      for (int kc=0;kc<4;++kc)
        qf[rb][kc] = *reinterpret_cast<const bf16x8*>(Qp + kc*32 + g*8);
    }

    float mrun[2][4], lrun[2][4];
    f32x4 acc[2][8];
    #pragma unroll
    for (int rb=0;rb<2;++rb){
      #pragma unroll
      for (int v=0;v<4;++v){ mrun[rb][v] = -1e30f; lrun[rb][v] = 0.f; }
      #pragma unroll
      for (int fn=0;fn<8;++fn) acc[rb][fn] = {0.f,0.f,0.f,0.f};
    }

    u16x8 vp[2];
    auto stageK = [&](int buf, int t){
      #pragma unroll
      for (int j=0;j<2;++j){
        int ci = j*512 + tid;
        int r = ci >> 4, cb = ci & 15;
        const char* src = (const char*)(Kh + (size_t)(t*64 + r)*H_*D_) + ((cb ^ (r & 7)) * 16);
        gload_lds16(src, (char*)Klds[buf] + (j*512 + wid*64)*16);
      }
    };
    auto loadV = [&](int t){
      const u16* sp = Vh + (size_t)(t*64 + kvp*2)*H_*D_ + dc*8;
      vp[0] = *reinterpret_cast<const u16x8*>(sp);
      vp[1] = *reinterpret_cast<const u16x8*>(sp + H_*D_);
    };
    auto writeVtB = [&](){
      #pragma unroll
      for (int e=0;e<8;++e){
        int r = dc*8 + e;
        int swz = (r ^ (r >> 3)) & 7;
        int addr = r*128 + (((kvp >> 2) ^ swz) << 4) + ((kvp << 2) & 12);
        *reinterpret_cast<uint32_t*>(VtB + addr) =
            (uint32_t)vp[0][e] | ((uint32_t)vp[1][e] << 16);
      }
    };

    stageK(0, t0);
    loadV(t0);
    writeVtB();
    bar_full();

    int cur = 0;
    for (int t=t0; t<t1; ++t){
      const bool more = (t+1 < t1);
      if (more){ stageK(cur^1, t+1); loadV(t+1); }

      f32x4 sc[2][4];
      #pragma unroll
      for (int fc=0;fc<4;++fc){
        int r = fc*16 + li;
        bf16x8 kf[4];
        #pragma unroll
        for (int kc=0;kc<4;++kc)
          kf[kc] = *reinterpret_cast<const bf16x8*>((const char*)Klds[cur] + r*256 + (((4*kc + g) ^ (r & 7))*16));
        __builtin_amdgcn_s_setprio(1);
        #pragma unroll
        for (int rb=0;rb<2;++rb){
          f32x4 s = {0.f,0.f,0.f,0.f};
          #pragma unroll
          for (int kc=0;kc<4;++kc)
            s = mfma16(qf[rb][kc], kf[kc], s);
          sc[rb][fc] = s;
        }
        __builtin_amdgcn_s_setprio(0);
      }

      const int c0 = t*64;
      if (t >= 4*qx){
        #pragma unroll
        for (int rb=0;rb<2;++rb){
          const int rowg = qb + wid*32 + rb*16 + g*4;
          #pragma unroll
          for (int fc=0;fc<4;++fc){
            int col = c0 + fc*16 + li;
            #pragma unroll
            for (int v=0;v<4;++v)
              if (col > rowg + v) sc[rb][fc][v] = -1e30f;
          }
        }
      }

      #pragma unroll
      for (int rb=0;rb<2;++rb){
        float tm[4];
        #pragma unroll
        for (int v=0;v<4;++v){
          float m2 = fmaxf(fmaxf(sc[rb][0][v], sc[rb][1][v]), fmaxf(sc[rb][2][v], sc[rb][3][v]));
          m2 = fmaxf(m2, __shfl_xor(m2, 1));
          m2 = fmaxf(m2, __shfl_xor(m2, 2));
          m2 = fmaxf(m2, __shfl_xor(m2, 4));
          m2 = fmaxf(m2, __shfl_xor(m2, 8));
          tm[v] = m2;
        }
        bool need = false;
        #pragma unroll
        for (int v=0;v<4;++v) need = need || (tm[v] > mrun[rb][v] + 8.f);
        if (__any(need)){
          float al[4];
          #pragma unroll
          for (int v=0;v<4;++v){
            float mnew = fmaxf(mrun[rb][v], tm[v]);
            al[v] = __expf(mrun[rb][v] - mnew);
            mrun[rb][v] = mnew;
            lrun[rb][v] *= al[v];
          }
          #pragma unroll
          for (int fn=0;fn<8;++fn)
            #pragma unroll
            for (int v=0;v<4;++v) acc[rb][fn][v] *= al[v];
        }
        float rs[4] = {0.f,0.f,0.f,0.f};
        #pragma unroll
        for (int fc=0;fc<4;++fc){
          #pragma unroll
          for (int v=0;v<4;++v){
            float p = __expf(sc[rb][fc][v] - mrun[rb][v]);
            rs[v] += p;
            int prow = rb*16 + g*4 + v;
            int pchunk = (fc*2 + (li>>3)) ^ (prow & 7);
            Plds[wid][prow*64 + pchunk*8 + (li & 7)] = (bf16)p;
          }
        }
        #pragma unroll
        for (int v=0;v<4;++v){
          float r = rs[v];
          r += __shfl_xor(r, 1); r += __shfl_xor(r, 2);
          r += __shfl_xor(r, 4); r += __shfl_xor(r, 8);
          lrun[rb][v] += r;
        }
      }

      bf16x8 pa[2][2];
      #pragma unroll
      for (int rb=0;rb<2;++rb)
        #pragma unroll
        for (int kc=0;kc<2;++kc)
          pa[rb][kc] = *reinterpret_cast<const bf16x8*>(
              &Plds[wid][(rb*16 + li)*64 + (((kc*4 + g) ^ (li & 7))<<3)]);
      #pragma unroll
      for (int fn=0;fn<8;++fn){
        int r = fn*16 + li;
        int swz = (r ^ (r >> 3)) & 7;
        bf16x8 bv[2];
        #pragma unroll
        for (int kc=0;kc<2;++kc)
          bv[kc] = *reinterpret_cast<const bf16x8*>(VtB + r*128 + (((kc*4 + g) ^ swz) << 4));
        __builtin_amdgcn_s_setprio(1);
        #pragma unroll
        for (int rb=0;rb<2;++rb)
          #pragma unroll
          for (int kc=0;kc<2;++kc)
            acc[rb][fn] = mfma16(pa[rb][kc], bv[kc], acc[rb][fn]);
        __builtin_amdgcn_s_setprio(0);
      }

      if (more){
        bar_lgkm();
        writeVtB();
      }
      bar_full();
      cur ^= 1;
    }

    const int dsel = it_dst[idx];
    float* MLd = ML + (size_t)(bh*18 + idx)*512;
    if (dsel == 0){
      #pragma unroll
      for (int rb=0;rb<2;++rb){
        #pragma unroll
        for (int v=0;v<4;++v){
          float inv = 1.f / lrun[rb][v];
          int rl = wid*32 + rb*16 + g*4 + v;
          bf16* dst = O + headoff + (size_t)(qb + rl)*H_*D_ + li;
          #pragma unroll
          for (int fn=0;fn<8;++fn)
            dst[fn*16] = (bf16)(acc[rb][fn][v] * inv);
          if (li == 0){ MLd[rl*2] = mrun[rb][v]; MLd[rl*2+1] = lrun[rb][v]; }
        }
      }
    } else {
      bf16* Od = OPb + (size_t)(bh*10 + dsel - 1)*256*128;
      #pragma unroll
      for (int rb=0;rb<2;++rb){
        #pragma unroll
        for (int v=0;v<4;++v){
          float inv = 1.f / lrun[rb][v];
          int rl = wid*32 + rb*16 + g*4 + v;
          #pragma unroll
          for (int fn=0;fn<8;++fn)
            Od[rl*128 + fn*16 + li] = (bf16)(acc[rb][fn][v] * inv);
          if (li == 0){ MLd[rl*2] = mrun[rb][v]; MLd[rl*2+1] = lrun[rb][v]; }
        }
      }
    }
  }
}

// ---------------- merge split partials into O ----------------
__global__ __launch_bounds__(256) void k_merge(const bf16* __restrict__ OPb, const float* __restrict__ ML,
                                               bf16* __restrict__ O){
  const int gid = blockIdx.x;         // 192 = 6 groups x 32 bh
  const int gsel = gid >> 5, bh = gid & 31;
  const int qx = mg_qx[gsel], np = mg_np[gsel], ss = mg_ss[gsel];
  const int b = bh >> 4, h = bh & 15;
  const int row = threadIdx.x;

  float m[4], l[4], wgt[4];
  #pragma unroll
  for (int j=0;j<4;++j){
    if (j < np){
      const float* mlp = ML + (size_t)(bh*18 + mg_mlf[gsel*4 + j])*512 + row*2;
      m[j] = mlp[0]; l[j] = mlp[1];
    } else { m[j] = -1e30f; l[j] = 0.f; }
  }
  float mm = fmaxf(fmaxf(m[0], m[1]), fmaxf(m[2], m[3]));
  float wsum = 0.f;
  #pragma unroll
  for (int j=0;j<4;++j){ wgt[j] = l[j]*__expf(m[j]-mm); wsum += wgt[j]; }
  float inv = 1.f/wsum;
  #pragma unroll
  for (int j=0;j<4;++j) wgt[j] *= inv;

  bf16* dst = O + (((size_t)b*S_ + qx*256 + row)*H_ + h)*D_;
  const bf16* s1 = OPb + (size_t)(bh*10 + ss + 0)*256*128 + row*128;
  const bf16* s2 = OPb + (size_t)(bh*10 + ss + 1)*256*128 + row*128;
  const bf16* s3 = OPb + (size_t)(bh*10 + ss + 2)*256*128 + row*128;
  #pragma unroll
  for (int c=0;c<128;c+=8){
    bf16x8 a = *reinterpret_cast<const bf16x8*>(dst + c);
    float acc8[8];
    #pragma unroll
    for (int i=0;i<8;++i) acc8[i] = (float)a[i]*wgt[0];
    bf16x8 p1 = *reinterpret_cast<const bf16x8*>(s1 + c);
    #pragma unroll
    for (int i=0;i<8;++i) acc8[i] += (float)p1[i]*wgt[1];
    if (np > 2){
      bf16x8 p2 = *reinterpret_cast<const bf16x8*>(s2 + c);
      #pragma unroll
      for (int i=0;i<8;++i) acc8[i] += (float)p2[i]*wgt[2];
    }
    if (np > 3){
      bf16x8 p3 = *reinterpret_cast<const bf16x8*>(s3 + c);
      #pragma unroll
      for (int i=0;i<8;++i) acc8[i] += (float)p3[i]*wgt[3];
    }
    bf16x8 o;
    #pragma unroll
    for (int i=0;i<8;++i) o[i] = (bf16)acc8[i];
    *reinterpret_cast<bf16x8*>(dst + c) = o;
  }
}

extern "C" void kernel_launch(void* const* d_in, const int* in_sizes, int n_in,
                              void* d_out, int out_size, void* d_ws, size_t ws_size,
                              hipStream_t stream)
{
  (void)in_sizes; (void)n_in; (void)out_size; (void)ws_size;
  const float* hid   = (const float*)d_in[0];
  const float* smask = (const float*)d_in[1];
  const float* samat = (const float*)d_in[2];
  const int*   pos   = (const int*)d_in[4];
  const float* Wq = (const float*)d_in[5];
  const float* Wk = (const float*)d_in[6];
  const float* Wv = (const float*)d_in[7];
  const float* Wo = (const float*)d_in[8];
  float* out = (float*)d_out;
  char* ws = (char*)d_ws;

  const size_t SZ_TAB = (size_t)S_*64*4;        // 512 KB per table
  const size_t SZ_BSH = (size_t)B_*S_*HID_*2;   // 16 MB bf16 [B,S,HID]
  float* cosT = (float*)(ws);
  float* sinT = (float*)(ws + SZ_TAB);
  bf16* buf1 = (bf16*)(ws + 2*SZ_TAB);                 // hidden_bf -> v
  bf16* buf2 = (bf16*)(ws + 2*SZ_TAB + 1*SZ_BSH);      // hiddenT  -> k
  bf16* buf3 = (bf16*)(ws + 2*SZ_TAB + 2*SZ_BSH);      // samat_bf -> q
  bf16* buf4 = (bf16*)(ws + 2*SZ_TAB + 3*SZ_BSH);      // hm -> attention O
  bf16* Wqb = (bf16*)(ws + 2*SZ_TAB + 4*SZ_BSH);
  bf16* Wkb = Wqb + (size_t)HID_*HID_;
  bf16* Wvb = Wkb + (size_t)HID_*HID_;
  bf16* Wob = Wvb + (size_t)HID_*HID_;
  // flash scratch aliases dead Wq/Wk/Wv region: 320 slots x 64KB = 20MB + ML 1.2MB <= 24MB
  bf16* OPb = Wqb;
  float* ML = (float*)((char*)Wqb + (size_t)320*256*128*2);

  k_tables<<<512,256,0,stream>>>(cosT, sinT);
  k_cvt_all<<<dim3(8192,5),256,0,stream>>>(samat, buf3,
                                           Wq, Wqb, Wk, Wkb, Wv, Wvb, Wo, Wob);
  k_transpose_cvt<<<dim3(32,32,2),256,0,stream>>>(hid, buf2, buf1);

  const size_t sBat = (size_t)S_*HID_;
  // G1: hm = sum_attn_mask @ hidden + (1-m)*hidden   (batched, dense — R12 proven)
  k_gemm_nt<1><<<dim3(16,16,2),256,0,stream>>>(buf3, buf2, buf4, 2048, sBat, sBat, sBat, 2048, smask, hid);
  // G2: q = hidden_bf @ Wq^T
  k_gemm_nt<0><<<dim3(16,32,1),256,0,stream>>>(buf1, Wqb, buf3, 2048, 0,0,0, 2048, nullptr, nullptr);
  k_rope<<<4096,256,0,stream>>>(buf3, cosT, sinT, pos, 0.08838834764831845f);  // q: pre-scaled
  // G3+G4 fused: [k|v] = hm @ [Wk|Wv]^T  (m201-body 256^2 engine)
  k_g8<<<dim3(256),512,0,stream>>>(buf4, Wkb, buf2, buf1);
  k_rope<<<4096,256,0,stream>>>(buf2, cosT, sinT, nullptr, 1.0f);
  // attention: O -> buf4 (hm dead); split partials -> OPb/ML
  k_flash<<<dim3(512),512,0,stream>>>(buf3, buf2, buf1, buf4, OPb, ML);
  k_merge<<<dim3(192),256,0,stream>>>(OPb, ML, buf4);
  // G5: out = O @ Wo^T -> fp32
  k_gemm_nt<2><<<dim3(16,32,1),256,0,stream>>>(buf4, Wob, out, 2048, 0,0,0, 2048, nullptr, nullptr);
}

// Round 15
// 411.142 us; speedup vs baseline: 1.0455x; 1.0076x over previous
//
#include <hip/hip_runtime.h>
#include <cstdint>
#include <cstddef>

#define B_   2
#define S_   2048
#define H_   16
#define D_   128
#define HID_ 2048

typedef __bf16 bf16;
typedef unsigned short u16;
typedef bf16 bf16x4 __attribute__((ext_vector_type(4)));
typedef bf16 bf16x8 __attribute__((ext_vector_type(8)));
typedef u16  u16x8  __attribute__((ext_vector_type(8)));
typedef float f32x4 __attribute__((ext_vector_type(4)));

__device__ unsigned g_work;   // work-stealing counter; zeroed by k_tables each launch

// flash item tables: 18 items per bh, heavy-first, makespan-balanced (R12)
__device__ const int it_qx[18]  = {7,7,6,4,4,2,6,6,5,5,5,3,3,1,7,7,0,2};
__device__ const int it_t0[18]  = {0,10,0,0,10,0,10,19,0,8,16,0,8,0,20,26,0,10};
__device__ const int it_t1[18]  = {10,20,10,10,20,10,19,28,8,16,24,8,16,8,26,32,4,12};
__device__ const int it_dst[18] = {0,1,0,0,8,0,4,5,0,6,7,0,9,0,2,3,0,10};
__device__ const int mg_qx[6]  = {7,6,5,4,3,2};
__device__ const int mg_np[6]  = {4,3,3,2,2,2};
__device__ const int mg_ss[6]  = {0,3,5,7,8,9};
__device__ const int mg_mlf[24] = {0,1,14,15,  2,6,7,0,  8,9,10,0,  3,4,0,0,  11,12,0,0,  5,17,0,0};

__device__ __forceinline__ f32x4 mfma16(bf16x8 a, bf16x8 b, f32x4 c){
  return __builtin_amdgcn_mfma_f32_16x16x32_bf16(a, b, c, 0, 0, 0);
}

__device__ __forceinline__ void gload_lds16(const void* g, void* l){
  __builtin_amdgcn_global_load_lds((const __attribute__((address_space(1))) void*)g,
                                   (__attribute__((address_space(3))) void*)l, 16, 0, 0);
}

__device__ __forceinline__ void bar_lgkm(){
  asm volatile("s_waitcnt lgkmcnt(0)" ::: "memory");
  __builtin_amdgcn_s_barrier();
}
__device__ __forceinline__ void bar_full(){
  asm volatile("s_waitcnt vmcnt(0) lgkmcnt(0)" ::: "memory");
  __builtin_amdgcn_s_barrier();
}

// ---------------- RoPE tables (+ work counter reset) ----------------
__global__ void k_tables(float* __restrict__ cosT, float* __restrict__ sinT){
  if (blockIdx.x == 0 && threadIdx.x == 0) g_work = 0u;
  int id = blockIdx.x*256 + threadIdx.x;      // S*64 = 131072 exact
  int p = id >> 6, i = id & 63;
  double f = (double)p * pow(10000.0, -(double)i/64.0);
  cosT[id] = (float)cos(f);
  sinT[id] = (float)sin(f);
}

// ---------------- fused fp32 -> bf16 converts (5 segments: samat + 4 weights) ----------------
__global__ void k_cvt_all(const float* __restrict__ a1, bf16* __restrict__ o1,
                          const float* __restrict__ w0, bf16* __restrict__ q0,
                          const float* __restrict__ w1, bf16* __restrict__ q1,
                          const float* __restrict__ w2, bf16* __restrict__ q2,
                          const float* __restrict__ w3, bf16* __restrict__ q3){
  const float* src; bf16* dst; int n4;
  switch (blockIdx.y){
    case 0: src = a1; dst = o1; n4 = 2097152; break;
    case 1: src = w0; dst = q0; n4 = 1048576; break;
    case 2: src = w1; dst = q1; n4 = 1048576; break;
    case 3: src = w2; dst = q2; n4 = 1048576; break;
    default: src = w3; dst = q3; n4 = 1048576; break;
  }
  int i = blockIdx.x*256 + threadIdx.x;
  if (i >= n4) return;
  f32x4 v = *reinterpret_cast<const f32x4*>(src + (size_t)i*4);
  bf16x4 o;
  o[0]=(bf16)v[0]; o[1]=(bf16)v[1]; o[2]=(bf16)v[2]; o[3]=(bf16)v[3];
  *reinterpret_cast<bf16x4*>(dst + (size_t)i*4) = o;
}

// ---- hidden [B][S][HID] f32 -> hiddenT [B][HID][S] bf16 + hidden_bf (fused convert) ----
__global__ __launch_bounds__(256) void k_transpose_cvt(const float* __restrict__ in, bf16* __restrict__ out,
                                                       bf16* __restrict__ hbf){
  __shared__ bf16 t[64][72];
  const int tid = threadIdx.x;
  const int b = blockIdx.z, j0 = blockIdx.x*64, s0 = blockIdx.y*64;
  #pragma unroll
  for (int u0 = 0; u0 < 4; ++u0){
    int u = u0*256 + tid;
    int r = u >> 4, c4 = (u & 15)*4;
    size_t off = ((size_t)b*S_ + s0 + r)*HID_ + j0 + c4;
    f32x4 v = *reinterpret_cast<const f32x4*>(in + off);
    bf16x4 o; o[0]=(bf16)v[0]; o[1]=(bf16)v[1]; o[2]=(bf16)v[2]; o[3]=(bf16)v[3];
    *reinterpret_cast<bf16x4*>(&t[r][c4]) = o;
    *reinterpret_cast<bf16x4*>(hbf + off) = o;
  }
  __syncthreads();
  #pragma unroll
  for (int u0 = 0; u0 < 4; ++u0){
    int u = u0*256 + tid;
    int r = u >> 4, c4 = (u & 15)*4;    // r: j-local, c4: s-local
    bf16x4 o;
    o[0] = t[c4+0][r]; o[1] = t[c4+1][r]; o[2] = t[c4+2][r]; o[3] = t[c4+3][r];
    *reinterpret_cast<bf16x4*>(out + ((size_t)b*HID_ + j0 + r)*S_ + s0 + c4) = o;
  }
}

// ---------------- NT GEMM 128x128: C[M,N] = A[M,K] * B[N,K]^T, bf16 in, fp32 acc ----------------
// EPI 0: bf16. EPI 1: += (1-mask[row])*hbf[row,col] (bf16 read), bf16 out (batched). EPI 2: fp32.
template<int EPI>
__global__ __launch_bounds__(256) void k_gemm_nt(
    const bf16* __restrict__ A, const bf16* __restrict__ Bm, void* __restrict__ Cv,
    int Kd, size_t sAz, size_t sBz, size_t sCz, int N,
    const float* __restrict__ mask, const bf16* __restrict__ hbf)
{
  const int tid = threadIdx.x;
  const int wid = tid >> 6, lane = tid & 63;
  const int g = lane >> 4, li = lane & 15;
  const int z = blockIdx.z;
  const int m0 = blockIdx.y*128, n0 = blockIdx.x*128;
  const int wm = wid >> 1, wn = wid & 1;
  const bf16* Ab = A + (size_t)z*sAz;
  const bf16* Bb = Bm + (size_t)z*sBz;

  __shared__ bf16 lA[128*64];
  __shared__ bf16 lB[128*64];

  f32x4 acc[4][4];
  #pragma unroll
  for (int i=0;i<4;++i)
    #pragma unroll
    for (int j=0;j<4;++j)
      acc[i][j] = {0.f,0.f,0.f,0.f};

  for (int k0 = 0; k0 < Kd; k0 += 64){
    #pragma unroll
    for (int j=0;j<4;++j){
      int ci = j*256 + tid;
      int r = ci >> 3, cb = ci & 7;
      gload_lds16(Ab + (size_t)(m0 + r)*Kd + k0 + cb*8, (char*)lA + (j*256 + wid*64)*16);
      gload_lds16(Bb + (size_t)(n0 + r)*Kd + k0 + cb*8, (char*)lB + (j*256 + wid*64)*16);
    }
    __syncthreads();
    #pragma unroll
    for (int kk=0;kk<2;++kk){
      bf16x8 af[4], bfm[4];
      #pragma unroll
      for (int i=0;i<4;++i){
        af[i]  = *reinterpret_cast<const bf16x8*>(&lA[(wm*64 + i*16 + li)*64 + kk*32 + g*8]);
        bfm[i] = *reinterpret_cast<const bf16x8*>(&lB[(wn*64 + i*16 + li)*64 + kk*32 + g*8]);
      }
      #pragma unroll
      for (int i=0;i<4;++i)
        #pragma unroll
        for (int j=0;j<4;++j)
          acc[i][j] = mfma16(af[i], bfm[j], acc[i][j]);
    }
    __syncthreads();
  }

  #pragma unroll
  for (int i=0;i<4;++i){
    #pragma unroll
    for (int j=0;j<4;++j){
      #pragma unroll
      for (int v=0;v<4;++v){
        int row = m0 + wm*64 + i*16 + g*4 + v;
        int col = n0 + wn*64 + j*16 + li;
        float x = acc[i][j][v];
        if (EPI == 1){
          x += (1.f - mask[z*S_ + row]) * (float)hbf[((size_t)z*S_ + row)*HID_ + col];
          ((bf16*)Cv)[(size_t)z*sCz + (size_t)row*N + col] = (bf16)x;
        } else if (EPI == 0){
          ((bf16*)Cv)[(size_t)row*N + col] = (bf16)x;
        } else if (EPI == 2){
          ((float*)Cv)[(size_t)row*N + col] = x;
        }
      }
    }
  }
}

// ---------------- G34 engine: 256x256 NT GEMM, 8 waves, m201 4-phase body ----------------
__global__ __launch_bounds__(512) void k_g8(
    const bf16* __restrict__ A, const bf16* __restrict__ Bm,
    bf16* __restrict__ Ck, bf16* __restrict__ Cvv)
{
  const int tid = threadIdx.x;
  const int wid = tid >> 6, lane = tid & 63;
  const int g = lane >> 4, li = lane & 15;
  const int wm = wid >> 2, wn = wid & 3;
  const int sb = (blockIdx.x & 7)*32 + (blockIdx.x >> 3);
  const int m0 = (sb >> 4)*256, n0 = (sb & 15)*256;
  const bf16* Ab = A  + (size_t)m0*HID_;
  const bf16* Bb = Bm + (size_t)n0*HID_;

  __shared__ bf16 lA[2][256*64];
  __shared__ bf16 lB[2][256*64];

  const int rr0 = tid >> 3, cc = tid & 7;
  const int rr1 = rr0 + 64;
  const int cx0 = cc ^ (rr0 & 7);
  const int cx1 = cc ^ (rr1 & 7);

  f32x4 acc[8][4];
  #pragma unroll
  for (int i=0;i<8;++i)
    #pragma unroll
    for (int j=0;j<4;++j) acc[i][j] = {0.f,0.f,0.f,0.f};

  auto stage = [&](int buf, int kt, int matsel, int half){
    const bf16* s = matsel ? Bb : Ab;
    char* dbase = (char*)(matsel ? lB[buf] : lA[buf]) + half*16384;
    gload_lds16(s + (size_t)(half*128 + rr0)*HID_ + kt*64 + cx0*8, dbase + (wid*64)*16);
    gload_lds16(s + (size_t)(half*128 + rr1)*HID_ + kt*64 + cx1*8, dbase + (512 + wid*64)*16);
  };
  auto rdA = [&](int buf, int i, int kh){
    int row = wm*128 + i*16 + li;
    return *reinterpret_cast<const bf16x8*>((const char*)lA[buf] + row*128 + (((kh*4 + g) ^ (row & 7))*16));
  };
  auto rdB = [&](int buf, int j, int kh){
    int row = wn*64 + j*16 + li;
    return *reinterpret_cast<const bf16x8*>((const char*)lB[buf] + row*128 + (((kh*4 + g) ^ (row & 7))*16));
  };

  const int NT = HID_ >> 6;
  stage(0,0,0,0); stage(0,0,0,1); stage(0,0,1,0); stage(0,0,1,1);

  int cur = 0;
  for (int kt = 0; kt < NT; ++kt){
    const bool more = (kt+1 < NT);
    bf16x8 af[4], bfr[4];

    if (more){
      stage(cur^1, kt+1, 0, 0);
      stage(cur^1, kt+1, 0, 1);
      stage(cur^1, kt+1, 1, 0);
      asm volatile("s_waitcnt vmcnt(6)" ::: "memory");
    } else {
      asm volatile("s_waitcnt vmcnt(0)" ::: "memory");
    }
    __builtin_amdgcn_s_barrier();

    // phase 0
    #pragma unroll
    for (int i=0;i<4;++i) af[i] = rdA(cur, i, 0);
    #pragma unroll
    for (int j=0;j<4;++j) bfr[j] = rdB(cur, j, 0);
    if (more) stage(cur^1, kt+1, 1, 1);
    __builtin_amdgcn_s_barrier();
    asm volatile("s_waitcnt lgkmcnt(0)" ::: "memory");
    __builtin_amdgcn_sched_barrier(0);
    __builtin_amdgcn_s_setprio(1);
    #pragma unroll
    for (int i=0;i<4;++i)
      #pragma unroll
      for (int j=0;j<4;++j) acc[i][j] = mfma16(af[i], bfr[j], acc[i][j]);
    __builtin_amdgcn_s_setprio(0);
    __builtin_amdgcn_s_barrier();

    // phase 1
    #pragma unroll
    for (int i=0;i<4;++i) af[i] = rdA(cur, i+4, 0);
    __builtin_amdgcn_s_barrier();
    asm volatile("s_waitcnt lgkmcnt(0)" ::: "memory");
    __builtin_amdgcn_sched_barrier(0);
    __builtin_amdgcn_s_setprio(1);
    #pragma unroll
    for (int i=0;i<4;++i)
      #pragma unroll
      for (int j=0;j<4;++j) acc[i+4][j] = mfma16(af[i], bfr[j], acc[i+4][j]);
    __builtin_amdgcn_s_setprio(0);
    __builtin_amdgcn_s_barrier();

    // phase 2
    #pragma unroll
    for (int i=0;i<4;++i) af[i] = rdA(cur, i, 1);
    #pragma unroll
    for (int j=0;j<4;++j) bfr[j] = rdB(cur, j, 1);
    __builtin_amdgcn_s_barrier();
    asm volatile("s_waitcnt lgkmcnt(0)" ::: "memory");
    __builtin_amdgcn_sched_barrier(0);
    __builtin_amdgcn_s_setprio(1);
    #pragma unroll
    for (int i=0;i<4;++i)
      #pragma unroll
      for (int j=0;j<4;++j) acc[i][j] = mfma16(af[i], bfr[j], acc[i][j]);
    __builtin_amdgcn_s_setprio(0);
    __builtin_amdgcn_s_barrier();

    // phase 3
    #pragma unroll
    for (int i=0;i<4;++i) af[i] = rdA(cur, i+4, 1);
    __builtin_amdgcn_s_barrier();
    asm volatile("s_waitcnt lgkmcnt(0)" ::: "memory");
    __builtin_amdgcn_sched_barrier(0);
    __builtin_amdgcn_s_setprio(1);
    #pragma unroll
    for (int i=0;i<4;++i)
      #pragma unroll
      for (int j=0;j<4;++j) acc[i+4][j] = mfma16(af[i], bfr[j], acc[i+4][j]);
    __builtin_amdgcn_s_setprio(0);
    __builtin_amdgcn_s_barrier();

    cur ^= 1;
  }

  #pragma unroll
  for (int i=0;i<8;++i){
    #pragma unroll
    for (int j=0;j<4;++j){
      #pragma unroll
      for (int v=0;v<4;++v){
        int row = m0 + wm*128 + i*16 + g*4 + v;
        int col = n0 + wn*64 + j*16 + li;
        float x = acc[i][j][v];
        if (col < 2048) Ck[(size_t)row*2048 + col] = (bf16)x;
        else            Cvv[(size_t)row*2048 + col - 2048] = (bf16)x;
      }
    }
  }
}

// ---------------- fused RoPE: blocks [0,4096) -> Q (scaled, pos), [4096,8192) -> K ----------------
__global__ void k_rope2(bf16* __restrict__ Qb, bf16* __restrict__ Kb, const float* __restrict__ cosT,
                        const float* __restrict__ sinT, const int* __restrict__ pos){
  const bool isQ = blockIdx.x < 4096;
  bf16* X = isQ ? Qb : Kb;
  int id = (isQ ? blockIdx.x : (blockIdx.x - 4096))*256 + threadIdx.x;
  int d4 = (id & 15)*4;
  int h  = (id >> 4) & 15;
  int s  = (id >> 8) & 2047;
  int b  = id >> 19;
  int p = isQ ? pos[b*S_ + s] : s;
  const float scale = isQ ? 0.08838834764831845f : 1.0f;
  size_t base = (((size_t)b*S_ + s)*H_ + h)*D_ + d4;
  f32x4 c  = *reinterpret_cast<const f32x4*>(cosT + (size_t)p*64 + d4);
  f32x4 sn = *reinterpret_cast<const f32x4*>(sinT + (size_t)p*64 + d4);
  bf16x4 x1 = *reinterpret_cast<bf16x4*>(X + base);
  bf16x4 x2 = *reinterpret_cast<bf16x4*>(X + base + 64);
  bf16x4 o1, o2;
  #pragma unroll
  for (int i=0;i<4;++i){
    float a = (float)x1[i], bb = (float)x2[i];
    o1[i] = (bf16)((a*c[i] - bb*sn[i])*scale);
    o2[i] = (bf16)((bb*c[i] + a*sn[i])*scale);
  }
  *reinterpret_cast<bf16x4*>(X + base) = o1;
  *reinterpret_cast<bf16x4*>(X + base + 64) = o2;
}

// ---------------- causal flash attention (R12 structure, unchanged) ----------------
__global__ __launch_bounds__(512,2) void k_flash(const bf16* __restrict__ Q, const bf16* __restrict__ K,
                                                 const bf16* __restrict__ V, bf16* __restrict__ O,
                                                 bf16* __restrict__ OPb, float* __restrict__ ML)
{
  const int tid = threadIdx.x;
  const int wid = tid >> 6, lane = tid & 63;
  const int g = lane >> 4, li = lane & 15;

  __shared__ bf16 Klds[2][64*128];
  __shared__ char VtB[128*128];
  __shared__ bf16 Plds[8][32*64];
  int* sip = (int*)&Plds[0][0];

  const int dc = tid & 15, kvp = tid >> 4;

  for (;;) {
    if (tid == 0) *sip = (int)atomicAdd(&g_work, 1u);
    __syncthreads();
    const int w = *sip;
    if (w >= 576) return;

    const int idx = w >> 5, bh = w & 31;
    const int qx = it_qx[idx], t0 = it_t0[idx], t1 = it_t1[idx];

    const int qb = qx * 256;
    const size_t headoff = ((size_t)(bh >> 4)*S_*H_ + (bh & 15))*D_;
    const bf16* Kh = K + headoff;
    const u16*  Vh = (const u16*)(V + headoff);

    bf16x8 qf[2][4];
    #pragma unroll
    for (int rb=0;rb<2;++rb){
      const bf16* Qp = Q + headoff + (size_t)(qb + wid*32 + rb*16 + li)*H_*D_;
      #pragma unroll
      for (int kc=0;kc<4;++kc)
        qf[rb][kc] = *reinterpret_cast<const bf16x8*>(Qp + kc*32 + g*8);
    }

    float mrun[2][4], lrun[2][4];
    f32x4 acc[2][8];
    #pragma unroll
    for (int rb=0;rb<2;++rb){
      #pragma unroll
      for (int v=0;v<4;++v){ mrun[rb][v] = -1e30f; lrun[rb][v] = 0.f; }
      #pragma unroll
      for (int fn=0;fn<8;++fn) acc[rb][fn] = {0.f,0.f,0.f,0.f};
    }

    u16x8 vp[2];
    auto stageK = [&](int buf, int t){
      #pragma unroll
      for (int j=0;j<2;++j){
        int ci = j*512 + tid;
        int r = ci >> 4, cb = ci & 15;
        const char* src = (const char*)(Kh + (size_t)(t*64 + r)*H_*D_) + ((cb ^ (r & 7)) * 16);
        gload_lds16(src, (char*)Klds[buf] + (j*512 + wid*64)*16);
      }
    };
    auto loadV = [&](int t){
      const u16* sp = Vh + (size_t)(t*64 + kvp*2)*H_*D_ + dc*8;
      vp[0] = *reinterpret_cast<const u16x8*>(sp);
      vp[1] = *reinterpret_cast<const u16x8*>(sp + H_*D_);
    };
    auto writeVtB = [&](){
      #pragma unroll
      for (int e=0;e<8;++e){
        int r = dc*8 + e;
        int swz = (r ^ (r >> 3)) & 7;
        int addr = r*128 + (((kvp >> 2) ^ swz) << 4) + ((kvp << 2) & 12);
        *reinterpret_cast<uint32_t*>(VtB + addr) =
            (uint32_t)vp[0][e] | ((uint32_t)vp[1][e] << 16);
      }
    };

    stageK(0, t0);
    loadV(t0);
    writeVtB();
    bar_full();

    int cur = 0;
    for (int t=t0; t<t1; ++t){
      const bool more = (t+1 < t1);
      if (more){ stageK(cur^1, t+1); loadV(t+1); }

      f32x4 sc[2][4];
      #pragma unroll
      for (int fc=0;fc<4;++fc){
        int r = fc*16 + li;
        bf16x8 kf[4];
        #pragma unroll
        for (int kc=0;kc<4;++kc)
          kf[kc] = *reinterpret_cast<const bf16x8*>((const char*)Klds[cur] + r*256 + (((4*kc + g) ^ (r & 7))*16));
        __builtin_amdgcn_s_setprio(1);
        #pragma unroll
        for (int rb=0;rb<2;++rb){
          f32x4 s = {0.f,0.f,0.f,0.f};
          #pragma unroll
          for (int kc=0;kc<4;++kc)
            s = mfma16(qf[rb][kc], kf[kc], s);
          sc[rb][fc] = s;
        }
        __builtin_amdgcn_s_setprio(0);
      }

      const int c0 = t*64;
      if (t >= 4*qx){
        #pragma unroll
        for (int rb=0;rb<2;++rb){
          const int rowg = qb + wid*32 + rb*16 + g*4;
          #pragma unroll
          for (int fc=0;fc<4;++fc){
            int col = c0 + fc*16 + li;
            #pragma unroll
            for (int v=0;v<4;++v)
              if (col > rowg + v) sc[rb][fc][v] = -1e30f;
          }
        }
      }

      #pragma unroll
      for (int rb=0;rb<2;++rb){
        float tm[4];
        #pragma unroll
        for (int v=0;v<4;++v){
          float m2 = fmaxf(fmaxf(sc[rb][0][v], sc[rb][1][v]), fmaxf(sc[rb][2][v], sc[rb][3][v]));
          m2 = fmaxf(m2, __shfl_xor(m2, 1));
          m2 = fmaxf(m2, __shfl_xor(m2, 2));
          m2 = fmaxf(m2, __shfl_xor(m2, 4));
          m2 = fmaxf(m2, __shfl_xor(m2, 8));
          tm[v] = m2;
        }
        bool need = false;
        #pragma unroll
        for (int v=0;v<4;++v) need = need || (tm[v] > mrun[rb][v] + 8.f);
        if (__any(need)){
          float al[4];
          #pragma unroll
          for (int v=0;v<4;++v){
            float mnew = fmaxf(mrun[rb][v], tm[v]);
            al[v] = __expf(mrun[rb][v] - mnew);
            mrun[rb][v] = mnew;
            lrun[rb][v] *= al[v];
          }
          #pragma unroll
          for (int fn=0;fn<8;++fn)
            #pragma unroll
            for (int v=0;v<4;++v) acc[rb][fn][v] *= al[v];
        }
        float rs[4] = {0.f,0.f,0.f,0.f};
        #pragma unroll
        for (int fc=0;fc<4;++fc){
          #pragma unroll
          for (int v=0;v<4;++v){
            float p = __expf(sc[rb][fc][v] - mrun[rb][v]);
            rs[v] += p;
            int prow = rb*16 + g*4 + v;
            int pchunk = (fc*2 + (li>>3)) ^ (prow & 7);
            Plds[wid][prow*64 + pchunk*8 + (li & 7)] = (bf16)p;
          }
        }
        #pragma unroll
        for (int v=0;v<4;++v){
          float r = rs[v];
          r += __shfl_xor(r, 1); r += __shfl_xor(r, 2);
          r += __shfl_xor(r, 4); r += __shfl_xor(r, 8);
          lrun[rb][v] += r;
        }
      }

      bf16x8 pa[2][2];
      #pragma unroll
      for (int rb=0;rb<2;++rb)
        #pragma unroll
        for (int kc=0;kc<2;++kc)
          pa[rb][kc] = *reinterpret_cast<const bf16x8*>(
              &Plds[wid][(rb*16 + li)*64 + (((kc*4 + g) ^ (li & 7))<<3)]);
      #pragma unroll
      for (int fn=0;fn<8;++fn){
        int r = fn*16 + li;
        int swz = (r ^ (r >> 3)) & 7;
        bf16x8 bv[2];
        #pragma unroll
        for (int kc=0;kc<2;++kc)
          bv[kc] = *reinterpret_cast<const bf16x8*>(VtB + r*128 + (((kc*4 + g) ^ swz) << 4));
        __builtin_amdgcn_s_setprio(1);
        #pragma unroll
        for (int rb=0;rb<2;++rb)
          #pragma unroll
          for (int kc=0;kc<2;++kc)
            acc[rb][fn] = mfma16(pa[rb][kc], bv[kc], acc[rb][fn]);
        __builtin_amdgcn_s_setprio(0);
      }

      if (more){
        bar_lgkm();
        writeVtB();
      }
      bar_full();
      cur ^= 1;
    }

    const int dsel = it_dst[idx];
    float* MLd = ML + (size_t)(bh*18 + idx)*512;
    if (dsel == 0){
      #pragma unroll
      for (int rb=0;rb<2;++rb){
        #pragma unroll
        for (int v=0;v<4;++v){
          float inv = 1.f / lrun[rb][v];
          int rl = wid*32 + rb*16 + g*4 + v;
          bf16* dst = O + headoff + (size_t)(qb + rl)*H_*D_ + li;
          #pragma unroll
          for (int fn=0;fn<8;++fn)
            dst[fn*16] = (bf16)(acc[rb][fn][v] * inv);
          if (li == 0){ MLd[rl*2] = mrun[rb][v]; MLd[rl*2+1] = lrun[rb][v]; }
        }
      }
    } else {
      bf16* Od = OPb + (size_t)(bh*10 + dsel - 1)*256*128;
      #pragma unroll
      for (int rb=0;rb<2;++rb){
        #pragma unroll
        for (int v=0;v<4;++v){
          float inv = 1.f / lrun[rb][v];
          int rl = wid*32 + rb*16 + g*4 + v;
          #pragma unroll
          for (int fn=0;fn<8;++fn)
            Od[rl*128 + fn*16 + li] = (bf16)(acc[rb][fn][v] * inv);
          if (li == 0){ MLd[rl*2] = mrun[rb][v]; MLd[rl*2+1] = lrun[rb][v]; }
        }
      }
    }
  }
}

// ---------------- merge split partials into O ----------------
__global__ __launch_bounds__(256) void k_merge(const bf16* __restrict__ OPb, const float* __restrict__ ML,
                                               bf16* __restrict__ O){
  const int gid = blockIdx.x;         // 192 = 6 groups x 32 bh
  const int gsel = gid >> 5, bh = gid & 31;
  const int qx = mg_qx[gsel], np = mg_np[gsel], ss = mg_ss[gsel];
  const int b = bh >> 4, h = bh & 15;
  const int row = threadIdx.x;

  float m[4], l[4], wgt[4];
  #pragma unroll
  for (int j=0;j<4;++j){
    if (j < np){
      const float* mlp = ML + (size_t)(bh*18 + mg_mlf[gsel*4 + j])*512 + row*2;
      m[j] = mlp[0]; l[j] = mlp[1];
    } else { m[j] = -1e30f; l[j] = 0.f; }
  }
  float mm = fmaxf(fmaxf(m[0], m[1]), fmaxf(m[2], m[3]));
  float wsum = 0.f;
  #pragma unroll
  for (int j=0;j<4;++j){ wgt[j] = l[j]*__expf(m[j]-mm); wsum += wgt[j]; }
  float inv = 1.f/wsum;
  #pragma unroll
  for (int j=0;j<4;++j) wgt[j] *= inv;

  bf16* dst = O + (((size_t)b*S_ + qx*256 + row)*H_ + h)*D_;
  const bf16* s1 = OPb + (size_t)(bh*10 + ss + 0)*256*128 + row*128;
  const bf16* s2 = OPb + (size_t)(bh*10 + ss + 1)*256*128 + row*128;
  const bf16* s3 = OPb + (size_t)(bh*10 + ss + 2)*256*128 + row*128;
  #pragma unroll
  for (int c=0;c<128;c+=8){
    bf16x8 a = *reinterpret_cast<const bf16x8*>(dst + c);
    float acc8[8];
    #pragma unroll
    for (int i=0;i<8;++i) acc8[i] = (float)a[i]*wgt[0];
    bf16x8 p1 = *reinterpret_cast<const bf16x8*>(s1 + c);
    #pragma unroll
    for (int i=0;i<8;++i) acc8[i] += (float)p1[i]*wgt[1];
    if (np > 2){
      bf16x8 p2 = *reinterpret_cast<const bf16x8*>(s2 + c);
      #pragma unroll
      for (int i=0;i<8;++i) acc8[i] += (float)p2[i]*wgt[2];
    }
    if (np > 3){
      bf16x8 p3 = *reinterpret_cast<const bf16x8*>(s3 + c);
      #pragma unroll
      for (int i=0;i<8;++i) acc8[i] += (float)p3[i]*wgt[3];
    }
    bf16x8 o;
    #pragma unroll
    for (int i=0;i<8;++i) o[i] = (bf16)acc8[i];
    *reinterpret_cast<bf16x8*>(dst + c) = o;
  }
}

extern "C" void kernel_launch(void* const* d_in, const int* in_sizes, int n_in,
                              void* d_out, int out_size, void* d_ws, size_t ws_size,
                              hipStream_t stream)
{
  (void)in_sizes; (void)n_in; (void)out_size; (void)ws_size;
  const float* hid   = (const float*)d_in[0];
  const float* smask = (const float*)d_in[1];
  const float* samat = (const float*)d_in[2];
  const int*   pos   = (const int*)d_in[4];
  const float* Wq = (const float*)d_in[5];
  const float* Wk = (const float*)d_in[6];
  const float* Wv = (const float*)d_in[7];
  const float* Wo = (const float*)d_in[8];
  float* out = (float*)d_out;
  char* ws = (char*)d_ws;

  const size_t SZ_TAB = (size_t)S_*64*4;        // 512 KB per table
  const size_t SZ_BSH = (size_t)B_*S_*HID_*2;   // 16 MB bf16 [B,S,HID]
  float* cosT = (float*)(ws);
  float* sinT = (float*)(ws + SZ_TAB);
  bf16* buf1 = (bf16*)(ws + 2*SZ_TAB);                 // hidden_bf -> v
  bf16* buf2 = (bf16*)(ws + 2*SZ_TAB + 1*SZ_BSH);      // hiddenT  -> k
  bf16* buf3 = (bf16*)(ws + 2*SZ_TAB + 2*SZ_BSH);      // samat_bf -> q
  bf16* buf4 = (bf16*)(ws + 2*SZ_TAB + 3*SZ_BSH);      // hm -> attention O
  bf16* Wqb = (bf16*)(ws + 2*SZ_TAB + 4*SZ_BSH);
  bf16* Wkb = Wqb + (size_t)HID_*HID_;
  bf16* Wvb = Wkb + (size_t)HID_*HID_;
  bf16* Wob = Wvb + (size_t)HID_*HID_;
  // flash scratch aliases dead Wq/Wk/Wv region: 320 slots x 64KB = 20MB + ML 1.2MB <= 24MB
  bf16* OPb = Wqb;
  float* ML = (float*)((char*)Wqb + (size_t)320*256*128*2);

  k_tables<<<512,256,0,stream>>>(cosT, sinT);
  k_cvt_all<<<dim3(8192,5),256,0,stream>>>(samat, buf3,
                                           Wq, Wqb, Wk, Wkb, Wv, Wvb, Wo, Wob);
  k_transpose_cvt<<<dim3(32,32,2),256,0,stream>>>(hid, buf2, buf1);

  const size_t sBat = (size_t)S_*HID_;
  // G1: hm = sum_attn_mask @ hidden + (1-m)*hidden_bf   (batched, dense; bf16 epilogue read)
  k_gemm_nt<1><<<dim3(16,16,2),256,0,stream>>>(buf3, buf2, buf4, 2048, sBat, sBat, sBat, 2048, smask, buf1);
  // G2: q = hidden_bf @ Wq^T
  k_gemm_nt<0><<<dim3(16,32,1),256,0,stream>>>(buf1, Wqb, buf3, 2048, 0,0,0, 2048, nullptr, nullptr);
  // G3+G4 fused: [k|v] = hm @ [Wk|Wv]^T  (m201-body 256^2 engine)
  k_g8<<<dim3(256),512,0,stream>>>(buf4, Wkb, buf2, buf1);
  // fused RoPE: q (scaled, pos) + k in one dispatch
  k_rope2<<<8192,256,0,stream>>>(buf3, buf2, cosT, sinT, pos);
  // attention: O -> buf4 (hm dead); split partials -> OPb/ML
  k_flash<<<dim3(512),512,0,stream>>>(buf3, buf2, buf1, buf4, OPb, ML);
  k_merge<<<dim3(192),256,0,stream>>>(OPb, ML, buf4);
  // G5: out = O @ Wo^T -> fp32
  k_gemm_nt<2><<<dim3(16,32,1),256,0,stream>>>(buf4, Wob, out, 2048, 0,0,0, 2048, nullptr, nullptr);
}